// Round 1
// baseline (2177.292 us; speedup 1.0000x reference)
//
#include <hip/hip_runtime.h>
#include <math.h>

#define NEG_SLOPE 0.2f

// ---------- helpers: order-preserving float<->uint for atomicMax ----------
__device__ __forceinline__ unsigned enc_f(float f) {
    unsigned u = __float_as_uint(f);
    return (u & 0x80000000u) ? ~u : (u | 0x80000000u);
}
__device__ __forceinline__ float dec_f(unsigned u) {
    return __uint_as_float((u & 0x80000000u) ? (u & 0x7fffffffu) : ~u);
}

// ---------- GEMM: out[N,256] = X[N,K] @ W[K,256] + b ----------
// 8 rows per block, 256 threads (thread = output column).
// X reads are wave-uniform -> scalar loads; W reads coalesced, L2-resident.
template <int K>
__global__ void gemm_bias_kernel(const float* __restrict__ X,
                                 const float* __restrict__ W,
                                 const float* __restrict__ b,
                                 float* __restrict__ out, int n_rows) {
    const int m = threadIdx.x;
    const int row0 = blockIdx.x * 8;
    float acc[8] = {0.f, 0.f, 0.f, 0.f, 0.f, 0.f, 0.f, 0.f};
    const float bm = b[m];
    for (int k = 0; k < K; ++k) {
        float w = W[(size_t)k * 256 + m];
#pragma unroll
        for (int r = 0; r < 8; ++r) {
            int row = row0 + r;
            if (row < n_rows) acc[r] += X[(size_t)row * K + k] * w;
        }
    }
#pragma unroll
    for (int r = 0; r < 8; ++r) {
        int row = row0 + r;
        if (row < n_rows) out[(size_t)row * 256 + m] = acc[r] + bm;
    }
}

// ---------- per-edge GATv2 score + atomic max ----------
// one 64-lane wave per edge; lane = channel c; 4 heads per lane.
__global__ void edge_score_kernel(const int* __restrict__ src_idx,
                                  const int* __restrict__ dst_idx,
                                  const float* __restrict__ xl,
                                  const float* __restrict__ xr,
                                  const float* __restrict__ att,  // [4*64]
                                  float* __restrict__ score,      // [E4,4]
                                  unsigned* __restrict__ mmax,    // [N,4]
                                  int n_total, int n_real) {
    const int lane = threadIdx.x & 63;
    const int eid = blockIdx.x * 4 + (threadIdx.x >> 6);
    if (eid >= n_total) return;
    int s, d;
    if (eid < n_real) { s = src_idx[eid]; d = dst_idx[eid]; }
    else             { s = eid - n_real; d = s; }
    const float* xls = xl + (size_t)s * 256;
    const float* xrd = xr + (size_t)d * 256;
    float sc[4];
#pragma unroll
    for (int h = 0; h < 4; ++h) {
        float v = xls[h * 64 + lane] + xrd[h * 64 + lane];
        v = v > 0.f ? v : NEG_SLOPE * v;
        sc[h] = v * att[h * 64 + lane];
    }
#pragma unroll
    for (int off = 32; off > 0; off >>= 1) {
#pragma unroll
        for (int h = 0; h < 4; ++h) sc[h] += __shfl_down(sc[h], off, 64);
    }
    if (lane == 0) {
#pragma unroll
        for (int h = 0; h < 4; ++h) {
            score[(size_t)eid * 4 + h] = sc[h];
            atomicMax(&mmax[(size_t)d * 4 + h], enc_f(sc[h]));
        }
    }
}

// ---------- p = exp(score - max), atomic sum ----------
__global__ void edge_exp_kernel(const int* __restrict__ dst_idx,
                                float* __restrict__ score,
                                const unsigned* __restrict__ mmax,
                                float* __restrict__ ssum,
                                int n_total, int n_real) {
    const long long idx = (long long)blockIdx.x * 256 + threadIdx.x;
    if (idx >= (long long)n_total * 4) return;
    const int e = (int)(idx >> 2), h = (int)(idx & 3);
    const int d = (e < n_real) ? dst_idx[e] : e - n_real;
    const float mx = dec_f(mmax[(size_t)d * 4 + h]);
    const float p = expf(score[idx] - mx);
    score[idx] = p;
    atomicAdd(&ssum[(size_t)d * 4 + h], p);
}

// ---------- acc[dst] += p * xl[src] ----------
__global__ void edge_aggregate_kernel(const int* __restrict__ src_idx,
                                      const int* __restrict__ dst_idx,
                                      const float* __restrict__ xl,
                                      const float* __restrict__ p,
                                      float* __restrict__ acc,
                                      int n_total, int n_real) {
    const int lane = threadIdx.x & 63;
    const int eid = blockIdx.x * 4 + (threadIdx.x >> 6);
    if (eid >= n_total) return;
    int s, d;
    if (eid < n_real) { s = src_idx[eid]; d = dst_idx[eid]; }
    else             { s = eid - n_real; d = s; }
    const float* xls = xl + (size_t)s * 256;
    float* accd = acc + (size_t)d * 256;
#pragma unroll
    for (int h = 0; h < 4; ++h) {
        const float ph = p[(size_t)eid * 4 + h];
        atomicAdd(&accd[h * 64 + lane], ph * xls[h * 64 + lane]);
    }
}

// ---------- out = acc / s + bias (+ optional ELU) ----------
__global__ void epilogue_kernel(const float* __restrict__ acc,
                                const float* __restrict__ ssum,
                                const float* __restrict__ bias,
                                float* __restrict__ out,
                                int n_nodes, int apply_elu) {
    const long long idx = (long long)blockIdx.x * 256 + threadIdx.x;
    if (idx >= (long long)n_nodes * 256) return;
    const int n = (int)(idx >> 8);
    const int hc = (int)(idx & 255);
    const int h = hc >> 6;
    float v = acc[idx] / ssum[(size_t)n * 4 + h] + bias[hc];
    if (apply_elu) v = v > 0.f ? v : expm1f(v);
    out[idx] = v;
}

// ---------- row-wise log_softmax over 256 ----------
__global__ void log_softmax_kernel(const float* __restrict__ in,
                                   float* __restrict__ out, int n_nodes) {
    __shared__ float red[8];
    const int n = blockIdx.x;
    const int t = threadIdx.x;
    const int wave = t >> 6, lane = t & 63;
    const float v = in[(size_t)n * 256 + t];
    float mx = v;
#pragma unroll
    for (int off = 32; off > 0; off >>= 1) mx = fmaxf(mx, __shfl_down(mx, off, 64));
    if (lane == 0) red[wave] = mx;
    __syncthreads();
    if (t == 0) {
        float m2 = red[0];
        for (int i = 1; i < 4; ++i) m2 = fmaxf(m2, red[i]);
        red[4] = m2;
    }
    __syncthreads();
    mx = red[4];
    float ex = expf(v - mx);
    float sum = ex;
#pragma unroll
    for (int off = 32; off > 0; off >>= 1) sum += __shfl_down(sum, off, 64);
    if (lane == 0) red[wave] = sum;
    __syncthreads();
    if (t == 0) {
        float s2 = 0.f;
        for (int i = 0; i < 4; ++i) s2 += red[i];
        red[5] = logf(s2);
    }
    __syncthreads();
    out[(size_t)n * 256 + t] = v - mx - red[5];
}

extern "C" void kernel_launch(void* const* d_in, const int* in_sizes, int n_in,
                              void* d_out, int out_size, void* d_ws, size_t ws_size,
                              hipStream_t stream) {
    const float* x     = (const float*)d_in[0];
    const int*   edge  = (const int*)d_in[1];
    const float* Wl1   = (const float*)d_in[2];
    const float* bl1   = (const float*)d_in[3];
    const float* Wr1   = (const float*)d_in[4];
    const float* br1   = (const float*)d_in[5];
    const float* att1  = (const float*)d_in[6];
    const float* bias1 = (const float*)d_in[7];
    const float* Wl2   = (const float*)d_in[8];
    const float* bl2   = (const float*)d_in[9];
    const float* Wr2   = (const float*)d_in[10];
    const float* br2   = (const float*)d_in[11];
    const float* att2  = (const float*)d_in[12];
    const float* bias2 = (const float*)d_in[13];

    const int N  = in_sizes[0] / 64;   // 20000
    const int E  = in_sizes[1] / 2;    // 500000
    const int E4 = E + N;              // with self-loops
    const int* srcI = edge;
    const int* dstI = edge + E;

    const size_t NM = (size_t)N * 256;
    float*    A     = (float*)d_ws;          // NM
    float*    B     = A + NM;                // NM
    float*    C     = B + NM;                // NM
    float*    score = C + NM;                // E4*4
    unsigned* mmax  = (unsigned*)(score + (size_t)E4 * 4);  // N*4
    float*    ssum  = (float*)(mmax + (size_t)N * 4);       // N*4

    const int gemm_grid  = (N + 7) / 8;
    const int edge_grid  = (E4 + 3) / 4;
    const int eh_grid    = (int)(((long long)E4 * 4 + 255) / 256);
    const int nm_grid    = (int)((NM + 255) / 256);

    // ---------------- layer 1 ----------------
    gemm_bias_kernel<64><<<gemm_grid, 256, 0, stream>>>(x, Wl1, bl1, A, N);
    gemm_bias_kernel<64><<<gemm_grid, 256, 0, stream>>>(x, Wr1, br1, B, N);
    hipMemsetAsync(mmax, 0, (size_t)N * 4 * sizeof(unsigned), stream);
    hipMemsetAsync(ssum, 0, (size_t)N * 4 * sizeof(float), stream);
    edge_score_kernel<<<edge_grid, 256, 0, stream>>>(srcI, dstI, A, B, att1,
                                                     score, mmax, E4, E);
    edge_exp_kernel<<<eh_grid, 256, 0, stream>>>(dstI, score, mmax, ssum, E4, E);
    hipMemsetAsync(B, 0, NM * sizeof(float), stream);
    edge_aggregate_kernel<<<edge_grid, 256, 0, stream>>>(srcI, dstI, A, score, B,
                                                         E4, E);
    epilogue_kernel<<<nm_grid, 256, 0, stream>>>(B, ssum, bias1, B, N, 1);

    // ---------------- layer 2 ----------------
    gemm_bias_kernel<256><<<gemm_grid, 256, 0, stream>>>(B, Wl2, bl2, A, N);
    gemm_bias_kernel<256><<<gemm_grid, 256, 0, stream>>>(B, Wr2, br2, C, N);
    hipMemsetAsync(mmax, 0, (size_t)N * 4 * sizeof(unsigned), stream);
    hipMemsetAsync(ssum, 0, (size_t)N * 4 * sizeof(float), stream);
    edge_score_kernel<<<edge_grid, 256, 0, stream>>>(srcI, dstI, A, C, att2,
                                                     score, mmax, E4, E);
    edge_exp_kernel<<<eh_grid, 256, 0, stream>>>(dstI, score, mmax, ssum, E4, E);
    hipMemsetAsync(B, 0, NM * sizeof(float), stream);
    edge_aggregate_kernel<<<edge_grid, 256, 0, stream>>>(srcI, dstI, A, score, B,
                                                         E4, E);

    float* h2 = (float*)d_out;
    epilogue_kernel<<<nm_grid, 256, 0, stream>>>(B, ssum, bias2, h2, N, 0);
    log_softmax_kernel<<<N, 256, 0, stream>>>(h2, h2 + NM, N);
}

// Round 2
// 584.182 us; speedup vs baseline: 3.7271x; 3.7271x over previous
//
#include <hip/hip_runtime.h>
#include <math.h>

#define NEG_SLOPE 0.2f

// ================= CSR build =================
__global__ void hist_kernel(const int* __restrict__ dst, int* __restrict__ deg, int E) {
    int i = blockIdx.x * 256 + threadIdx.x;
    if (i < E) atomicAdd(&deg[dst[i]], 1);
}

// single-block exclusive scan over n (<= ~few 100k), 1024 threads
__global__ void scan_kernel(const int* __restrict__ deg, int* __restrict__ row_ptr, int n) {
    __shared__ int sm[1024];
    __shared__ int carry_s;
    const int t = threadIdx.x;
    if (t == 0) { carry_s = 0; row_ptr[0] = 0; }
    __syncthreads();
    for (int base = 0; base < n; base += 1024) {
        int v = (base + t < n) ? deg[base + t] : 0;
        sm[t] = v;
        __syncthreads();
        for (int off = 1; off < 1024; off <<= 1) {
            int u = (t >= off) ? sm[t - off] : 0;
            __syncthreads();
            sm[t] += u;
            __syncthreads();
        }
        if (base + t < n) row_ptr[base + t + 1] = carry_s + sm[t];
        __syncthreads();
        if (t == 0) carry_s += sm[1023];
        __syncthreads();
    }
}

__global__ void scatter_kernel(const int* __restrict__ src, const int* __restrict__ dst,
                               const int* __restrict__ row_ptr, int* __restrict__ cursor,
                               int* __restrict__ csr_src, int E) {
    int i = blockIdx.x * 256 + threadIdx.x;
    if (i < E) {
        int d = dst[i];
        int pos = row_ptr[d] + atomicAdd(&cursor[d], 1);
        csr_src[pos] = src[i];
    }
}

// ================= tiled fp32 GEMM: out[M,256] = X[M,K] @ W[K,256] + b =================
// BM=64, BN=64, BK=16; 256 threads; 4x4 microtile.
template <int K>
__global__ __launch_bounds__(256) void gemm_tile_kernel(const float* __restrict__ X,
                                                        const float* __restrict__ W,
                                                        const float* __restrict__ b,
                                                        float* __restrict__ out, int M) {
    __shared__ float As[16][68];  // padded: stride 68 floats = 272B (16B aligned, bank-shift 4)
    __shared__ float Bs[16][64];
    const int t = threadIdx.x;
    const int row0 = blockIdx.x * 64;
    const int col0 = blockIdx.y * 64;
    const int tx = t & 15, ty = t >> 4;
    const int ar = t >> 2, ak = (t & 3) * 4;   // A-load: row ar, cols ak..ak+3
    const int bk = t >> 4, bn = (t & 15) * 4;  // B-load: row bk, cols bn..bn+3
    float acc[4][4] = {};

    for (int k0 = 0; k0 < K; k0 += 16) {
        const int arow = row0 + ar;
        float4 a4 = make_float4(0.f, 0.f, 0.f, 0.f);
        if (arow < M) a4 = *(const float4*)&X[(size_t)arow * K + k0 + ak];
        As[ak + 0][ar] = a4.x;
        As[ak + 1][ar] = a4.y;
        As[ak + 2][ar] = a4.z;
        As[ak + 3][ar] = a4.w;
        float4 b4 = *(const float4*)&W[(size_t)(k0 + bk) * 256 + col0 + bn];
        *(float4*)&Bs[bk][bn] = b4;
        __syncthreads();
#pragma unroll
        for (int k = 0; k < 16; ++k) {
            float4 av = *(const float4*)&As[k][ty * 4];
            float4 bv = *(const float4*)&Bs[k][tx * 4];
            float a[4] = {av.x, av.y, av.z, av.w};
            float bb[4] = {bv.x, bv.y, bv.z, bv.w};
#pragma unroll
            for (int i = 0; i < 4; ++i)
#pragma unroll
                for (int j = 0; j < 4; ++j) acc[i][j] += a[i] * bb[j];
        }
        __syncthreads();
    }
#pragma unroll
    for (int i = 0; i < 4; ++i) {
        const int row = row0 + ty * 4 + i;
        if (row < M) {
            float4 o;
            o.x = acc[i][0] + b[col0 + tx * 4 + 0];
            o.y = acc[i][1] + b[col0 + tx * 4 + 1];
            o.z = acc[i][2] + b[col0 + tx * 4 + 2];
            o.w = acc[i][3] + b[col0 + tx * 4 + 3];
            *(float4*)&out[(size_t)row * 256 + col0 + tx * 4] = o;
        }
    }
}

// ================= fused GAT: score + online softmax + aggregate + epilogue =================
// one block (256 thr) per dst node; wave w = head w; lane = channel.
__global__ __launch_bounds__(256) void gat_fused_kernel(const int* __restrict__ csr_src,
                                                        const int* __restrict__ row_ptr,
                                                        const float* __restrict__ xl,
                                                        const float* __restrict__ xr,
                                                        const float* __restrict__ att,
                                                        const float* __restrict__ bias,
                                                        float* __restrict__ out,
                                                        int n_nodes, int apply_elu) {
    const int d = blockIdx.x;
    const int t = threadIdx.x;  // 0..255 ; head = t>>6, channel = t&63
    const float xrv = xr[(size_t)d * 256 + t];
    const float av = att[t];
    float m = -INFINITY, s = 0.f, acc = 0.f;
    const int e0 = row_ptr[d], e1 = row_ptr[d + 1];
    for (int e = e0; e <= e1; ++e) {            // e == e1 -> self loop
        const int sn = (e < e1) ? csr_src[e] : d;
        const float xlv = xl[(size_t)sn * 256 + t];
        float v = xlv + xrv;
        v = v > 0.f ? v : NEG_SLOPE * v;
        float sc = v * av;
#pragma unroll
        for (int off = 32; off > 0; off >>= 1) sc += __shfl_xor(sc, off, 64);
        // sc is bitwise-identical across the wave -> uniform branch
        if (sc > m) {
            const float f = __expf(m - sc);     // m==-inf -> 0
            acc *= f;
            s *= f;
            m = sc;
        }
        const float p = __expf(sc - m);
        s += p;
        acc += p * xlv;
    }
    float o = acc / s + bias[t];
    if (apply_elu) o = o > 0.f ? o : expm1f(o);
    out[(size_t)d * 256 + t] = o;
}

// ================= row-wise log_softmax over 256 =================
__global__ void log_softmax_kernel(const float* __restrict__ in,
                                   float* __restrict__ out, int n_nodes) {
    __shared__ float red[8];
    const int n = blockIdx.x;
    const int t = threadIdx.x;
    const int wave = t >> 6, lane = t & 63;
    const float v = in[(size_t)n * 256 + t];
    float mx = v;
#pragma unroll
    for (int off = 32; off > 0; off >>= 1) mx = fmaxf(mx, __shfl_xor(mx, off, 64));
    if (lane == 0) red[wave] = mx;
    __syncthreads();
    if (t == 0) {
        float m2 = red[0];
        for (int i = 1; i < 4; ++i) m2 = fmaxf(m2, red[i]);
        red[4] = m2;
    }
    __syncthreads();
    mx = red[4];
    float sum = __expf(v - mx);
#pragma unroll
    for (int off = 32; off > 0; off >>= 1) sum += __shfl_xor(sum, off, 64);
    if (lane == 0) red[wave] = sum;
    __syncthreads();
    if (t == 0) {
        float s2 = 0.f;
        for (int i = 0; i < 4; ++i) s2 += red[i];
        red[5] = logf(s2);
    }
    __syncthreads();
    out[(size_t)n * 256 + t] = v - mx - red[5];
}

extern "C" void kernel_launch(void* const* d_in, const int* in_sizes, int n_in,
                              void* d_out, int out_size, void* d_ws, size_t ws_size,
                              hipStream_t stream) {
    const float* x     = (const float*)d_in[0];
    const int*   edge  = (const int*)d_in[1];
    const float* Wl1   = (const float*)d_in[2];
    const float* bl1   = (const float*)d_in[3];
    const float* Wr1   = (const float*)d_in[4];
    const float* br1   = (const float*)d_in[5];
    const float* att1  = (const float*)d_in[6];
    const float* bias1 = (const float*)d_in[7];
    const float* Wl2   = (const float*)d_in[8];
    const float* bl2   = (const float*)d_in[9];
    const float* Wr2   = (const float*)d_in[10];
    const float* br2   = (const float*)d_in[11];
    const float* att2  = (const float*)d_in[12];
    const float* bias2 = (const float*)d_in[13];

    const int N = in_sizes[0] / 64;  // 20000
    const int E = in_sizes[1] / 2;   // 500000
    const int* srcI = edge;
    const int* dstI = edge + E;

    const size_t NM = (size_t)N * 256;
    float* A = (float*)d_ws;  // NM
    float* B = A + NM;        // NM
    float* C = B + NM;        // NM
    int* deg     = (int*)(C + NM);  // N
    int* row_ptr = deg + N;         // N+1
    int* cursor  = row_ptr + N + 1; // N
    int* csr_src = cursor + N;      // E

    const int e_grid = (E + 255) / 256;
    const dim3 gemm_grid((N + 63) / 64, 4);

    // ---- CSR by destination (recomputed every call; deterministic work) ----
    hipMemsetAsync(deg, 0, (size_t)N * sizeof(int), stream);
    hipMemsetAsync(cursor, 0, (size_t)N * sizeof(int), stream);
    hist_kernel<<<e_grid, 256, 0, stream>>>(dstI, deg, E);
    scan_kernel<<<1, 1024, 0, stream>>>(deg, row_ptr, N);
    scatter_kernel<<<e_grid, 256, 0, stream>>>(srcI, dstI, row_ptr, cursor, csr_src, E);

    // ---- layer 1 ----
    gemm_tile_kernel<64><<<gemm_grid, 256, 0, stream>>>(x, Wl1, bl1, A, N);
    gemm_tile_kernel<64><<<gemm_grid, 256, 0, stream>>>(x, Wr1, br1, B, N);
    gat_fused_kernel<<<N, 256, 0, stream>>>(csr_src, row_ptr, A, B, att1, bias1, C, N, 1);

    // ---- layer 2 ----
    gemm_tile_kernel<256><<<gemm_grid, 256, 0, stream>>>(C, Wl2, bl2, A, N);
    gemm_tile_kernel<256><<<gemm_grid, 256, 0, stream>>>(C, Wr2, br2, B, N);
    float* h2 = (float*)d_out;
    gat_fused_kernel<<<N, 256, 0, stream>>>(csr_src, row_ptr, A, B, att2, bias2, h2, N, 0);

    log_softmax_kernel<<<N, 256, 0, stream>>>(h2, h2 + NM, N);
}

// Round 3
// 419.201 us; speedup vs baseline: 5.1939x; 1.3936x over previous
//
#include <hip/hip_runtime.h>
#include <math.h>

#define NEG_SLOPE 0.2f

// ================= CSR build =================
__global__ void hist_kernel(const int* __restrict__ dst, int* __restrict__ deg, int E) {
    int i = blockIdx.x * 256 + threadIdx.x;
    if (i < E) atomicAdd(&deg[dst[i]], 1);
}

// single-block exclusive scan over n, 1024 threads
__global__ void scan_kernel(const int* __restrict__ deg, int* __restrict__ row_ptr, int n) {
    __shared__ int sm[1024];
    __shared__ int carry_s;
    const int t = threadIdx.x;
    if (t == 0) { carry_s = 0; row_ptr[0] = 0; }
    __syncthreads();
    for (int base = 0; base < n; base += 1024) {
        int v = (base + t < n) ? deg[base + t] : 0;
        sm[t] = v;
        __syncthreads();
        for (int off = 1; off < 1024; off <<= 1) {
            int u = (t >= off) ? sm[t - off] : 0;
            __syncthreads();
            sm[t] += u;
            __syncthreads();
        }
        if (base + t < n) row_ptr[base + t + 1] = carry_s + sm[t];
        __syncthreads();
        if (t == 0) carry_s += sm[1023];
        __syncthreads();
    }
}

__global__ void scatter_kernel(const int* __restrict__ src, const int* __restrict__ dst,
                               const int* __restrict__ row_ptr, int* __restrict__ cursor,
                               int* __restrict__ csr_src, int E) {
    int i = blockIdx.x * 256 + threadIdx.x;
    if (i < E) {
        int d = dst[i];
        int pos = row_ptr[d] + atomicAdd(&cursor[d], 1);
        csr_src[pos] = src[i];
    }
}

// ================= tiled fp32 GEMM: out[M,256] = X[M,K] @ W[K,256] + b =================
template <int K>
__global__ __launch_bounds__(256) void gemm_tile_kernel(const float* __restrict__ X,
                                                        const float* __restrict__ W,
                                                        const float* __restrict__ b,
                                                        float* __restrict__ out, int M) {
    __shared__ float As[16][68];
    __shared__ float Bs[16][64];
    const int t = threadIdx.x;
    const int row0 = blockIdx.x * 64;
    const int col0 = blockIdx.y * 64;
    const int tx = t & 15, ty = t >> 4;
    const int ar = t >> 2, ak = (t & 3) * 4;
    const int bk = t >> 4, bn = (t & 15) * 4;
    float acc[4][4] = {};

    for (int k0 = 0; k0 < K; k0 += 16) {
        const int arow = row0 + ar;
        float4 a4 = make_float4(0.f, 0.f, 0.f, 0.f);
        if (arow < M) a4 = *(const float4*)&X[(size_t)arow * K + k0 + ak];
        As[ak + 0][ar] = a4.x;
        As[ak + 1][ar] = a4.y;
        As[ak + 2][ar] = a4.z;
        As[ak + 3][ar] = a4.w;
        float4 b4 = *(const float4*)&W[(size_t)(k0 + bk) * 256 + col0 + bn];
        *(float4*)&Bs[bk][bn] = b4;
        __syncthreads();
#pragma unroll
        for (int k = 0; k < 16; ++k) {
            float4 av = *(const float4*)&As[k][ty * 4];
            float4 bv = *(const float4*)&Bs[k][tx * 4];
            float a[4] = {av.x, av.y, av.z, av.w};
            float bb[4] = {bv.x, bv.y, bv.z, bv.w};
#pragma unroll
            for (int i = 0; i < 4; ++i)
#pragma unroll
                for (int j = 0; j < 4; ++j) acc[i][j] += a[i] * bb[j];
        }
        __syncthreads();
    }
#pragma unroll
    for (int i = 0; i < 4; ++i) {
        const int row = row0 + ty * 4 + i;
        if (row < M) {
            float4 o;
            o.x = acc[i][0] + b[col0 + tx * 4 + 0];
            o.y = acc[i][1] + b[col0 + tx * 4 + 1];
            o.z = acc[i][2] + b[col0 + tx * 4 + 2];
            o.w = acc[i][3] + b[col0 + tx * 4 + 3];
            *(float4*)&out[(size_t)row * 256 + col0 + tx * 4] = o;
        }
    }
}

// ================= fused GAT, 8-edge batched =================
// one block per dst node; wave w = head w; lane = channel.
// Per chunk of 8 edges: 8 gathers in flight, fold-reduce (17 shfl), 1 exp,
// broadcast 8 p's, 8 FMA into per-lane accumulator.
__global__ __launch_bounds__(256) void gat_fused_kernel(const int* __restrict__ csr_src,
                                                        const int* __restrict__ row_ptr,
                                                        const float* __restrict__ xl,
                                                        const float* __restrict__ xr,
                                                        const float* __restrict__ att,
                                                        const float* __restrict__ bias,
                                                        float* __restrict__ out,
                                                        int n_nodes, int apply_elu) {
    const int d = blockIdx.x;
    const int t = threadIdx.x;          // head = t>>6, channel = t&63
    const int lane = t & 63;
    const float xrv = xr[(size_t)d * 256 + t];
    const float av = att[t];
    const int e0 = row_ptr[d];
    const int deg = row_ptr[d + 1] - e0;
    const int cnt = deg + 1;            // + self loop (edge index deg)
    const bool b0 = lane & 1, b1 = lane & 2, b2 = lane & 4;
    const int sel = lane & 7;           // which edge of the chunk this lane owns
    float m = -INFINITY, s = 0.f, acc = 0.f;

    for (int base = 0; base < cnt; base += 8) {
        int srcs[8];
#pragma unroll
        for (int i = 0; i < 8; ++i) {
            const int j = base + i;
            srcs[i] = (j < deg) ? csr_src[e0 + j] : d;   // pad & self-loop -> d
        }
        float xv[8];
#pragma unroll
        for (int i = 0; i < 8; ++i) xv[i] = xl[(size_t)srcs[i] * 256 + t];
        float sc[8];
#pragma unroll
        for (int i = 0; i < 8; ++i) {
            float v = xv[i] + xrv;
            v = v > 0.f ? v : NEG_SLOPE * v;
            sc[i] = v * av;
        }
        // ---- fold 8 registers -> 1: lane L ends with full score of edge (L&7)
        float a0 = sc[0] + __shfl_xor(sc[0], 1, 64);
        float a1 = sc[1] + __shfl_xor(sc[1], 1, 64);
        float a2 = sc[2] + __shfl_xor(sc[2], 1, 64);
        float a3 = sc[3] + __shfl_xor(sc[3], 1, 64);
        float a4 = sc[4] + __shfl_xor(sc[4], 1, 64);
        float a5 = sc[5] + __shfl_xor(sc[5], 1, 64);
        float a6 = sc[6] + __shfl_xor(sc[6], 1, 64);
        float a7 = sc[7] + __shfl_xor(sc[7], 1, 64);
        float p0 = b0 ? a1 : a0;
        float p1 = b0 ? a3 : a2;
        float p2 = b0 ? a5 : a4;
        float p3 = b0 ? a7 : a6;
        float c0 = p0 + __shfl_xor(p0, 2, 64);
        float c1 = p1 + __shfl_xor(p1, 2, 64);
        float c2 = p2 + __shfl_xor(p2, 2, 64);
        float c3 = p3 + __shfl_xor(p3, 2, 64);
        float r0 = b1 ? c1 : c0;
        float r1 = b1 ? c3 : c2;
        float d0 = r0 + __shfl_xor(r0, 4, 64);
        float d1 = r1 + __shfl_xor(r1, 4, 64);
        float f = b2 ? d1 : d0;
        f += __shfl_xor(f, 8, 64);
        f += __shfl_xor(f, 16, 64);
        f += __shfl_xor(f, 32, 64);
        // mask pad edges AFTER the reduce
        f = (base + sel < cnt) ? f : -INFINITY;
        // chunk max (uniform across wave: every 8-lane group holds all 8 edges)
        float mx = fmaxf(f, __shfl_xor(f, 1, 64));
        mx = fmaxf(mx, __shfl_xor(mx, 2, 64));
        mx = fmaxf(mx, __shfl_xor(mx, 4, 64));
        if (mx > m) {
            const float g = __expf(m - mx);   // m==-inf -> 0
            acc *= g;
            s *= g;
            m = mx;
        }
        const float p = __expf(f - m);        // one exp per lane per 8 edges
        float pv[8];
#pragma unroll
        for (int i = 0; i < 8; ++i) pv[i] = __shfl(p, i, 64);
        s += ((pv[0] + pv[1]) + (pv[2] + pv[3])) + ((pv[4] + pv[5]) + (pv[6] + pv[7]));
#pragma unroll
        for (int i = 0; i < 8; ++i) acc = fmaf(pv[i], xv[i], acc);
    }
    float o = acc / s + bias[t];
    if (apply_elu) o = o > 0.f ? o : expm1f(o);
    out[(size_t)d * 256 + t] = o;
}

// ================= row-wise log_softmax over 256 =================
__global__ void log_softmax_kernel(const float* __restrict__ in,
                                   float* __restrict__ out, int n_nodes) {
    __shared__ float red[8];
    const int n = blockIdx.x;
    const int t = threadIdx.x;
    const int wave = t >> 6, lane = t & 63;
    const float v = in[(size_t)n * 256 + t];
    float mx = v;
#pragma unroll
    for (int off = 32; off > 0; off >>= 1) mx = fmaxf(mx, __shfl_xor(mx, off, 64));
    if (lane == 0) red[wave] = mx;
    __syncthreads();
    if (t == 0) {
        float m2 = red[0];
        for (int i = 1; i < 4; ++i) m2 = fmaxf(m2, red[i]);
        red[4] = m2;
    }
    __syncthreads();
    mx = red[4];
    float sum = __expf(v - mx);
#pragma unroll
    for (int off = 32; off > 0; off >>= 1) sum += __shfl_xor(sum, off, 64);
    if (lane == 0) red[wave] = sum;
    __syncthreads();
    if (t == 0) {
        float s2 = 0.f;
        for (int i = 0; i < 4; ++i) s2 += red[i];
        red[5] = logf(s2);
    }
    __syncthreads();
    out[(size_t)n * 256 + t] = v - mx - red[5];
}

extern "C" void kernel_launch(void* const* d_in, const int* in_sizes, int n_in,
                              void* d_out, int out_size, void* d_ws, size_t ws_size,
                              hipStream_t stream) {
    const float* x     = (const float*)d_in[0];
    const int*   edge  = (const int*)d_in[1];
    const float* Wl1   = (const float*)d_in[2];
    const float* bl1   = (const float*)d_in[3];
    const float* Wr1   = (const float*)d_in[4];
    const float* br1   = (const float*)d_in[5];
    const float* att1  = (const float*)d_in[6];
    const float* bias1 = (const float*)d_in[7];
    const float* Wl2   = (const float*)d_in[8];
    const float* bl2   = (const float*)d_in[9];
    const float* Wr2   = (const float*)d_in[10];
    const float* br2   = (const float*)d_in[11];
    const float* att2  = (const float*)d_in[12];
    const float* bias2 = (const float*)d_in[13];

    const int N = in_sizes[0] / 64;  // 20000
    const int E = in_sizes[1] / 2;   // 500000
    const int* srcI = edge;
    const int* dstI = edge + E;

    const size_t NM = (size_t)N * 256;
    float* A = (float*)d_ws;  // NM
    float* B = A + NM;        // NM
    float* C = B + NM;        // NM
    int* deg     = (int*)(C + NM);  // N
    int* row_ptr = deg + N;         // N+1
    int* cursor  = row_ptr + N + 1; // N
    int* csr_src = cursor + N;      // E

    const int e_grid = (E + 255) / 256;
    const dim3 gemm_grid((N + 63) / 64, 4);

    // ---- CSR by destination ----
    hipMemsetAsync(deg, 0, (size_t)N * sizeof(int), stream);
    hipMemsetAsync(cursor, 0, (size_t)N * sizeof(int), stream);
    hist_kernel<<<e_grid, 256, 0, stream>>>(dstI, deg, E);
    scan_kernel<<<1, 1024, 0, stream>>>(deg, row_ptr, N);
    scatter_kernel<<<e_grid, 256, 0, stream>>>(srcI, dstI, row_ptr, cursor, csr_src, E);

    // ---- layer 1 ----
    gemm_tile_kernel<64><<<gemm_grid, 256, 0, stream>>>(x, Wl1, bl1, A, N);
    gemm_tile_kernel<64><<<gemm_grid, 256, 0, stream>>>(x, Wr1, br1, B, N);
    gat_fused_kernel<<<N, 256, 0, stream>>>(csr_src, row_ptr, A, B, att1, bias1, C, N, 1);

    // ---- layer 2 ----
    gemm_tile_kernel<256><<<gemm_grid, 256, 0, stream>>>(C, Wl2, bl2, A, N);
    gemm_tile_kernel<256><<<gemm_grid, 256, 0, stream>>>(C, Wr2, br2, B, N);
    float* h2 = (float*)d_out;
    gat_fused_kernel<<<N, 256, 0, stream>>>(csr_src, row_ptr, A, B, att2, bias2, h2, N, 0);

    log_softmax_kernel<<<N, 256, 0, stream>>>(h2, h2 + NM, N);
}

// Round 4
// 405.500 us; speedup vs baseline: 5.3694x; 1.0338x over previous
//
#include <hip/hip_runtime.h>
#include <math.h>

#define NEG_SLOPE 0.2f

typedef unsigned short ushort_t;

__device__ __forceinline__ ushort_t f2bf(float f) {           // RNE
    unsigned u = __float_as_uint(f);
    return (ushort_t)((u + 0x7fffu + ((u >> 16) & 1u)) >> 16);
}
__device__ __forceinline__ float bf2f(ushort_t u) {
    return __uint_as_float(((unsigned)u) << 16);
}

// ================= CSR build =================
__global__ void hist_kernel(const int* __restrict__ dst, int* __restrict__ deg, int E) {
    int i = blockIdx.x * 256 + threadIdx.x;
    if (i < E) atomicAdd(&deg[dst[i]], 1);
}

__global__ void partial_kernel(const int* __restrict__ deg, int* __restrict__ partial, int n) {
    const int t = threadIdx.x;
    const int i = blockIdx.x * 256 + t;
    int v = (i < n) ? deg[i] : 0;
#pragma unroll
    for (int off = 32; off > 0; off >>= 1) v += __shfl_xor(v, off, 64);
    __shared__ int ws[4];
    if ((t & 63) == 0) ws[t >> 6] = v;
    __syncthreads();
    if (t == 0) partial[blockIdx.x] = ws[0] + ws[1] + ws[2] + ws[3];
}

// single-block exclusive scan (used for the ~80 block partials)
__global__ void scan_kernel(const int* __restrict__ in, int* __restrict__ out, int n) {
    __shared__ int sm[1024];
    __shared__ int carry_s;
    const int t = threadIdx.x;
    if (t == 0) { carry_s = 0; out[0] = 0; }
    __syncthreads();
    for (int base = 0; base < n; base += 1024) {
        int v = (base + t < n) ? in[base + t] : 0;
        sm[t] = v;
        __syncthreads();
        for (int off = 1; off < 1024; off <<= 1) {
            int u = (t >= off) ? sm[t - off] : 0;
            __syncthreads();
            sm[t] += u;
            __syncthreads();
        }
        if (base + t < n) out[base + t + 1] = carry_s + sm[t];
        __syncthreads();
        if (t == 0) carry_s += sm[1023];
        __syncthreads();
    }
}

__global__ void scan_block_kernel(const int* __restrict__ deg, const int* __restrict__ blk_off,
                                  int* __restrict__ row_ptr, int n) {
    const int t = threadIdx.x;
    const int i = blockIdx.x * 256 + t;
    const int lane = t & 63, w = t >> 6;
    int x = (i < n) ? deg[i] : 0;
#pragma unroll
    for (int off = 1; off < 64; off <<= 1) {
        int u = __shfl_up(x, off, 64);
        if (lane >= off) x += u;
    }
    __shared__ int ws[4];
    if (lane == 63) ws[w] = x;
    __syncthreads();
    int add = blk_off[blockIdx.x];
#pragma unroll
    for (int j = 0; j < 4; ++j)
        if (j < w) add += ws[j];
    if (i < n) row_ptr[i + 1] = add + x;
    if (i == 0) row_ptr[0] = 0;
}

__global__ void scatter_kernel(const int* __restrict__ src, const int* __restrict__ dst,
                               const int* __restrict__ row_ptr, int* __restrict__ cursor,
                               int* __restrict__ csr_src, int E) {
    int i = blockIdx.x * 256 + threadIdx.x;
    if (i < E) {
        int d = dst[i];
        int pos = row_ptr[d] + atomicAdd(&cursor[d], 1);
        csr_src[pos] = src[i];
    }
}

// ================= 128x128 tiled fp32 GEMM: out[M,256] = X[M,K] @ W[K,256] + b ========
// 256 threads, 8x8 microtile as 4 quadrants (+-64) so LDS reads stay <=2-way (free).
template <int K, bool OUT_BF16>
__global__ __launch_bounds__(256) void gemm128_kernel(const float* __restrict__ X,
                                                      const float* __restrict__ W,
                                                      const float* __restrict__ b,
                                                      void* __restrict__ outv, int M) {
    __shared__ float As[16][132];   // [k][row]
    __shared__ float Bs[16][132];   // [k][col]
    const int t = threadIdx.x;
    const int row0 = blockIdx.x * 128;
    const int col0 = blockIdx.y * 128;
    const int tx = t & 15, ty = t >> 4;
    const int ar = t >> 2, ak = (t & 3) * 4;   // A-load: row ar(+64), k ak..ak+3
    const int bk = t >> 4, bn = (t & 15) * 4;  // B-load: k bk, col bn(+64)
    float acc[8][8] = {};

    for (int k0 = 0; k0 < K; k0 += 16) {
#pragma unroll
        for (int h = 0; h < 2; ++h) {
            const int row = row0 + ar + h * 64;
            float4 a4 = make_float4(0.f, 0.f, 0.f, 0.f);
            if (row < M) a4 = *(const float4*)&X[(size_t)row * K + k0 + ak];
            As[ak + 0][ar + h * 64] = a4.x;
            As[ak + 1][ar + h * 64] = a4.y;
            As[ak + 2][ar + h * 64] = a4.z;
            As[ak + 3][ar + h * 64] = a4.w;
        }
#pragma unroll
        for (int h = 0; h < 2; ++h) {
            float4 b4 = *(const float4*)&W[(size_t)(k0 + bk) * 256 + col0 + bn + h * 64];
            *(float4*)&Bs[bk][bn + h * 64] = b4;
        }
        __syncthreads();
#pragma unroll
        for (int k = 0; k < 16; ++k) {
            float a[8], bb[8];
            *(float4*)&a[0]  = *(const float4*)&As[k][ty * 4];
            *(float4*)&a[4]  = *(const float4*)&As[k][64 + ty * 4];
            *(float4*)&bb[0] = *(const float4*)&Bs[k][tx * 4];
            *(float4*)&bb[4] = *(const float4*)&Bs[k][64 + tx * 4];
#pragma unroll
            for (int i = 0; i < 8; ++i)
#pragma unroll
                for (int j = 0; j < 8; ++j) acc[i][j] += a[i] * bb[j];
        }
        __syncthreads();
    }

    float bcol[8];
#pragma unroll
    for (int j = 0; j < 4; ++j) {
        bcol[j]     = b[col0 + tx * 4 + j];
        bcol[4 + j] = b[col0 + 64 + tx * 4 + j];
    }
#pragma unroll
    for (int ih = 0; ih < 2; ++ih) {
#pragma unroll
        for (int i = 0; i < 4; ++i) {
            const int row = row0 + ih * 64 + ty * 4 + i;
            if (row >= M) continue;
            const int ai = ih * 4 + i;
#pragma unroll
            for (int jh = 0; jh < 2; ++jh) {
                const int col = col0 + jh * 64 + tx * 4;
                if (OUT_BF16) {
                    ushort4 u;
                    u.x = f2bf(acc[ai][jh * 4 + 0] + bcol[jh * 4 + 0]);
                    u.y = f2bf(acc[ai][jh * 4 + 1] + bcol[jh * 4 + 1]);
                    u.z = f2bf(acc[ai][jh * 4 + 2] + bcol[jh * 4 + 2]);
                    u.w = f2bf(acc[ai][jh * 4 + 3] + bcol[jh * 4 + 3]);
                    *(ushort4*)&((ushort_t*)outv)[(size_t)row * 256 + col] = u;
                } else {
                    float4 o;
                    o.x = acc[ai][jh * 4 + 0] + bcol[jh * 4 + 0];
                    o.y = acc[ai][jh * 4 + 1] + bcol[jh * 4 + 1];
                    o.z = acc[ai][jh * 4 + 2] + bcol[jh * 4 + 2];
                    o.w = acc[ai][jh * 4 + 3] + bcol[jh * 4 + 3];
                    *(float4*)&((float*)outv)[(size_t)row * 256 + col] = o;
                }
            }
        }
    }
}

// ================= fused GAT (bf16 xl gathers) + optional fused log_softmax ==========
__global__ __launch_bounds__(256) void gat_fused_kernel(const int* __restrict__ csr_src,
                                                        const int* __restrict__ row_ptr,
                                                        const ushort_t* __restrict__ xl,
                                                        const float* __restrict__ xr,
                                                        const float* __restrict__ att,
                                                        const float* __restrict__ bias,
                                                        float* __restrict__ out,
                                                        float* __restrict__ out_ls,
                                                        int n_nodes, int apply_elu) {
    __shared__ float red[8];
    const int d = blockIdx.x;
    const int t = threadIdx.x;          // head = t>>6, channel = t&63
    const int lane = t & 63, w = t >> 6;
    const float xrv = xr[(size_t)d * 256 + t];
    const float av = att[t];
    const int e0 = row_ptr[d];
    const int deg = row_ptr[d + 1] - e0;
    const int cnt = deg + 1;            // + self loop
    const bool b0 = lane & 1, b1 = lane & 2, b2 = lane & 4;
    const int sel = lane & 7;
    float m = -INFINITY, s = 0.f, acc = 0.f;

    for (int base = 0; base < cnt; base += 8) {
        int srcs[8];
#pragma unroll
        for (int i = 0; i < 8; ++i) {
            const int j = base + i;
            srcs[i] = (j < deg) ? csr_src[e0 + j] : d;
        }
        float xv[8];
#pragma unroll
        for (int i = 0; i < 8; ++i) xv[i] = bf2f(xl[(size_t)srcs[i] * 256 + t]);
        float sc[8];
#pragma unroll
        for (int i = 0; i < 8; ++i) {
            float v = xv[i] + xrv;
            v = v > 0.f ? v : NEG_SLOPE * v;
            sc[i] = v * av;
        }
        float a0 = sc[0] + __shfl_xor(sc[0], 1, 64);
        float a1 = sc[1] + __shfl_xor(sc[1], 1, 64);
        float a2 = sc[2] + __shfl_xor(sc[2], 1, 64);
        float a3 = sc[3] + __shfl_xor(sc[3], 1, 64);
        float a4 = sc[4] + __shfl_xor(sc[4], 1, 64);
        float a5 = sc[5] + __shfl_xor(sc[5], 1, 64);
        float a6 = sc[6] + __shfl_xor(sc[6], 1, 64);
        float a7 = sc[7] + __shfl_xor(sc[7], 1, 64);
        float p0 = b0 ? a1 : a0;
        float p1 = b0 ? a3 : a2;
        float p2 = b0 ? a5 : a4;
        float p3 = b0 ? a7 : a6;
        float c0 = p0 + __shfl_xor(p0, 2, 64);
        float c1 = p1 + __shfl_xor(p1, 2, 64);
        float c2 = p2 + __shfl_xor(p2, 2, 64);
        float c3 = p3 + __shfl_xor(p3, 2, 64);
        float r0 = b1 ? c1 : c0;
        float r1 = b1 ? c3 : c2;
        float d0 = r0 + __shfl_xor(r0, 4, 64);
        float d1 = r1 + __shfl_xor(r1, 4, 64);
        float f = b2 ? d1 : d0;
        f += __shfl_xor(f, 8, 64);
        f += __shfl_xor(f, 16, 64);
        f += __shfl_xor(f, 32, 64);
        f = (base + sel < cnt) ? f : -INFINITY;
        float mx = fmaxf(f, __shfl_xor(f, 1, 64));
        mx = fmaxf(mx, __shfl_xor(mx, 2, 64));
        mx = fmaxf(mx, __shfl_xor(mx, 4, 64));
        if (mx > m) {
            const float g = __expf(m - mx);
            acc *= g;
            s *= g;
            m = mx;
        }
        const float p = __expf(f - m);
        float pv[8];
#pragma unroll
        for (int i = 0; i < 8; ++i) pv[i] = __shfl(p, i, 64);
        s += ((pv[0] + pv[1]) + (pv[2] + pv[3])) + ((pv[4] + pv[5]) + (pv[6] + pv[7]));
#pragma unroll
        for (int i = 0; i < 8; ++i) acc = fmaf(pv[i], xv[i], acc);
    }
    float o = acc / s + bias[t];
    if (apply_elu) {
        o = o > 0.f ? o : expm1f(o);
        out[(size_t)d * 256 + t] = o;
    } else {
        out[(size_t)d * 256 + t] = o;
        // fused row log_softmax over 256
        float mx = o;
#pragma unroll
        for (int off = 32; off > 0; off >>= 1) mx = fmaxf(mx, __shfl_xor(mx, off, 64));
        if (lane == 0) red[w] = mx;
        __syncthreads();
        const float m4 = fmaxf(fmaxf(red[0], red[1]), fmaxf(red[2], red[3]));
        float sum = __expf(o - m4);
#pragma unroll
        for (int off = 32; off > 0; off >>= 1) sum += __shfl_xor(sum, off, 64);
        if (lane == 0) red[4 + w] = sum;
        __syncthreads();
        const float s4 = (red[4] + red[5]) + (red[6] + red[7]);
        out_ls[(size_t)d * 256 + t] = o - m4 - logf(s4);
    }
}

extern "C" void kernel_launch(void* const* d_in, const int* in_sizes, int n_in,
                              void* d_out, int out_size, void* d_ws, size_t ws_size,
                              hipStream_t stream) {
    const float* x     = (const float*)d_in[0];
    const int*   edge  = (const int*)d_in[1];
    const float* Wl1   = (const float*)d_in[2];
    const float* bl1   = (const float*)d_in[3];
    const float* Wr1   = (const float*)d_in[4];
    const float* br1   = (const float*)d_in[5];
    const float* att1  = (const float*)d_in[6];
    const float* bias1 = (const float*)d_in[7];
    const float* Wl2   = (const float*)d_in[8];
    const float* bl2   = (const float*)d_in[9];
    const float* Wr2   = (const float*)d_in[10];
    const float* br2   = (const float*)d_in[11];
    const float* att2  = (const float*)d_in[12];
    const float* bias2 = (const float*)d_in[13];

    const int N = in_sizes[0] / 64;  // 20000
    const int E = in_sizes[1] / 2;   // 500000
    const int* srcI = edge;
    const int* dstI = edge + E;

    const size_t NM = (size_t)N * 256;
    float*    XR  = (float*)d_ws;             // NM floats (xr, fp32)
    float*    C   = XR + NM;                  // NM floats (layer-1 out)
    ushort_t* XLB = (ushort_t*)(C + NM);      // NM ushorts (xl, bf16)
    int* deg     = (int*)(XLB + NM);          // N
    int* row_ptr = deg + N;                   // N+1
    int* cursor  = row_ptr + N + 1;           // N
    int* partial = cursor + N;                // nb
    int* blk_off = partial + ((N + 255) / 256);  // nb+1
    int* csr_src = blk_off + ((N + 255) / 256) + 1;  // E

    const int nb = (N + 255) / 256;
    const int e_grid = (E + 255) / 256;
    const dim3 gemm_grid((N + 127) / 128, 2);

    // ---- CSR by destination ----
    hipMemsetAsync(deg, 0, (size_t)N * sizeof(int), stream);
    hipMemsetAsync(cursor, 0, (size_t)N * sizeof(int), stream);
    hist_kernel<<<e_grid, 256, 0, stream>>>(dstI, deg, E);
    partial_kernel<<<nb, 256, 0, stream>>>(deg, partial, N);
    scan_kernel<<<1, 1024, 0, stream>>>(partial, blk_off, nb);
    scan_block_kernel<<<nb, 256, 0, stream>>>(deg, blk_off, row_ptr, N);
    scatter_kernel<<<e_grid, 256, 0, stream>>>(srcI, dstI, row_ptr, cursor, csr_src, E);

    // ---- layer 1 ----
    gemm128_kernel<64, true><<<gemm_grid, 256, 0, stream>>>(x, Wl1, bl1, XLB, N);
    gemm128_kernel<64, false><<<gemm_grid, 256, 0, stream>>>(x, Wr1, br1, XR, N);
    gat_fused_kernel<<<N, 256, 0, stream>>>(csr_src, row_ptr, XLB, XR, att1, bias1,
                                            C, nullptr, N, 1);

    // ---- layer 2 ----
    gemm128_kernel<256, true><<<gemm_grid, 256, 0, stream>>>(C, Wl2, bl2, XLB, N);
    gemm128_kernel<256, false><<<gemm_grid, 256, 0, stream>>>(C, Wr2, br2, XR, N);
    float* h2 = (float*)d_out;
    gat_fused_kernel<<<N, 256, 0, stream>>>(csr_src, row_ptr, XLB, XR, att2, bias2,
                                            h2, h2 + NM, N, 0);
}

// Round 5
// 373.652 us; speedup vs baseline: 5.8271x; 1.0852x over previous
//
#include <hip/hip_runtime.h>
#include <math.h>

#define NEG_SLOPE 0.2f

typedef unsigned short ushort_t;

__device__ __forceinline__ ushort_t f2bf(float f) {           // RNE
    unsigned u = __float_as_uint(f);
    return (ushort_t)((u + 0x7fffu + ((u >> 16) & 1u)) >> 16);
}

// ================= CSR build =================
__global__ void hist_kernel(const int* __restrict__ dst, int* __restrict__ deg, int E) {
    int i = blockIdx.x * 256 + threadIdx.x;
    if (i < E) atomicAdd(&deg[dst[i]], 1);
}

__global__ void partial_kernel(const int* __restrict__ deg, int* __restrict__ partial, int n) {
    const int t = threadIdx.x;
    const int i = blockIdx.x * 256 + t;
    int v = (i < n) ? deg[i] : 0;
#pragma unroll
    for (int off = 32; off > 0; off >>= 1) v += __shfl_xor(v, off, 64);
    __shared__ int ws[4];
    if ((t & 63) == 0) ws[t >> 6] = v;
    __syncthreads();
    if (t == 0) partial[blockIdx.x] = ws[0] + ws[1] + ws[2] + ws[3];
}

__global__ void scan_kernel(const int* __restrict__ in, int* __restrict__ out, int n) {
    __shared__ int sm[1024];
    __shared__ int carry_s;
    const int t = threadIdx.x;
    if (t == 0) { carry_s = 0; out[0] = 0; }
    __syncthreads();
    for (int base = 0; base < n; base += 1024) {
        int v = (base + t < n) ? in[base + t] : 0;
        sm[t] = v;
        __syncthreads();
        for (int off = 1; off < 1024; off <<= 1) {
            int u = (t >= off) ? sm[t - off] : 0;
            __syncthreads();
            sm[t] += u;
            __syncthreads();
        }
        if (base + t < n) out[base + t + 1] = carry_s + sm[t];
        __syncthreads();
        if (t == 0) carry_s += sm[1023];
        __syncthreads();
    }
}

__global__ void scan_block_kernel(const int* __restrict__ deg, const int* __restrict__ blk_off,
                                  int* __restrict__ row_ptr, int n) {
    const int t = threadIdx.x;
    const int i = blockIdx.x * 256 + t;
    const int lane = t & 63, w = t >> 6;
    int x = (i < n) ? deg[i] : 0;
#pragma unroll
    for (int off = 1; off < 64; off <<= 1) {
        int u = __shfl_up(x, off, 64);
        if (lane >= off) x += u;
    }
    __shared__ int ws[4];
    if (lane == 63) ws[w] = x;
    __syncthreads();
    int add = blk_off[blockIdx.x];
#pragma unroll
    for (int j = 0; j < 4; ++j)
        if (j < w) add += ws[j];
    if (i < n) row_ptr[i + 1] = add + x;
    if (i == 0) row_ptr[0] = 0;
}

__global__ void scatter_kernel(const int* __restrict__ src, const int* __restrict__ dst,
                               const int* __restrict__ row_ptr, int* __restrict__ cursor,
                               int* __restrict__ csr_src, int E) {
    int i = blockIdx.x * 256 + threadIdx.x;
    if (i < E) {
        int d = dst[i];
        int pos = row_ptr[d] + atomicAdd(&cursor[d], 1);
        csr_src[pos] = src[i];
    }
}

// ================= 128x128 tiled fp32 GEMM: out[M,256] = X[M,K] @ W[K,256] + b ========
template <int K, bool OUT_BF16>
__global__ __launch_bounds__(256) void gemm128_kernel(const float* __restrict__ X,
                                                      const float* __restrict__ W,
                                                      const float* __restrict__ b,
                                                      void* __restrict__ outv, int M) {
    __shared__ float As[16][132];
    __shared__ float Bs[16][132];
    const int t = threadIdx.x;
    const int row0 = blockIdx.x * 128;
    const int col0 = blockIdx.y * 128;
    const int tx = t & 15, ty = t >> 4;
    const int ar = t >> 2, ak = (t & 3) * 4;
    const int bk = t >> 4, bn = (t & 15) * 4;
    float acc[8][8] = {};

    for (int k0 = 0; k0 < K; k0 += 16) {
#pragma unroll
        for (int h = 0; h < 2; ++h) {
            const int row = row0 + ar + h * 64;
            float4 a4 = make_float4(0.f, 0.f, 0.f, 0.f);
            if (row < M) a4 = *(const float4*)&X[(size_t)row * K + k0 + ak];
            As[ak + 0][ar + h * 64] = a4.x;
            As[ak + 1][ar + h * 64] = a4.y;
            As[ak + 2][ar + h * 64] = a4.z;
            As[ak + 3][ar + h * 64] = a4.w;
        }
#pragma unroll
        for (int h = 0; h < 2; ++h) {
            float4 b4 = *(const float4*)&W[(size_t)(k0 + bk) * 256 + col0 + bn + h * 64];
            *(float4*)&Bs[bk][bn + h * 64] = b4;
        }
        __syncthreads();
#pragma unroll
        for (int k = 0; k < 16; ++k) {
            float a[8], bb[8];
            *(float4*)&a[0]  = *(const float4*)&As[k][ty * 4];
            *(float4*)&a[4]  = *(const float4*)&As[k][64 + ty * 4];
            *(float4*)&bb[0] = *(const float4*)&Bs[k][tx * 4];
            *(float4*)&bb[4] = *(const float4*)&Bs[k][64 + tx * 4];
#pragma unroll
            for (int i = 0; i < 8; ++i)
#pragma unroll
                for (int j = 0; j < 8; ++j) acc[i][j] += a[i] * bb[j];
        }
        __syncthreads();
    }

    float bcol[8];
#pragma unroll
    for (int j = 0; j < 4; ++j) {
        bcol[j]     = b[col0 + tx * 4 + j];
        bcol[4 + j] = b[col0 + 64 + tx * 4 + j];
    }
#pragma unroll
    for (int ih = 0; ih < 2; ++ih) {
#pragma unroll
        for (int i = 0; i < 4; ++i) {
            const int row = row0 + ih * 64 + ty * 4 + i;
            if (row >= M) continue;
            const int ai = ih * 4 + i;
#pragma unroll
            for (int jh = 0; jh < 2; ++jh) {
                const int col = col0 + jh * 64 + tx * 4;
                if (OUT_BF16) {
                    ushort4 u;
                    u.x = f2bf(acc[ai][jh * 4 + 0] + bcol[jh * 4 + 0]);
                    u.y = f2bf(acc[ai][jh * 4 + 1] + bcol[jh * 4 + 1]);
                    u.z = f2bf(acc[ai][jh * 4 + 2] + bcol[jh * 4 + 2]);
                    u.w = f2bf(acc[ai][jh * 4 + 3] + bcol[jh * 4 + 3]);
                    *(ushort4*)&((ushort_t*)outv)[(size_t)row * 256 + col] = u;
                } else {
                    float4 o;
                    o.x = acc[ai][jh * 4 + 0] + bcol[jh * 4 + 0];
                    o.y = acc[ai][jh * 4 + 1] + bcol[jh * 4 + 1];
                    o.z = acc[ai][jh * 4 + 2] + bcol[jh * 4 + 2];
                    o.w = acc[ai][jh * 4 + 3] + bcol[jh * 4 + 3];
                    *(float4*)&((float*)outv)[(size_t)row * 256 + col] = o;
                }
            }
        }
    }
}

// ================= fused GAT, lane = (edge_slot, channel_group) =================
// Block = 1 dst node, wave w = head w. Lane eg=lane>>3 owns edge slot, cg=lane&7
// owns channels cg*8..cg*8+7. One uint4 gather per lane = 8 edges in 1 inst.
__global__ __launch_bounds__(256) void gat_fused_kernel(const int* __restrict__ csr_src,
                                                        const int* __restrict__ row_ptr,
                                                        const ushort_t* __restrict__ xl,
                                                        const float* __restrict__ xr,
                                                        const float* __restrict__ att,
                                                        const float* __restrict__ bias,
                                                        float* __restrict__ out,
                                                        float* __restrict__ out_ls,
                                                        int n_nodes, int apply_elu) {
    __shared__ float red[8];
    const int d = blockIdx.x;
    const int t = threadIdx.x;
    const int w = t >> 6;            // head
    const int lane = t & 63;
    const int eg = lane >> 3;        // edge slot 0..7
    const int cg = lane & 7;         // channel group 0..7

    float xrv[8], av[8];
    {
        const float* xrp = xr + (size_t)d * 256 + w * 64 + cg * 8;
        const float* ap  = att + w * 64 + cg * 8;
        *(float4*)&xrv[0] = *(const float4*)xrp;
        *(float4*)&xrv[4] = *(const float4*)(xrp + 4);
        *(float4*)&av[0]  = *(const float4*)ap;
        *(float4*)&av[4]  = *(const float4*)(ap + 4);
    }
    const int e0 = row_ptr[d];
    const int deg = row_ptr[d + 1] - e0;
    const int cnt = deg + 1;         // + self loop at index deg
    float m = -INFINITY, s_loc = 0.f;
    float acc8[8] = {0.f, 0.f, 0.f, 0.f, 0.f, 0.f, 0.f, 0.f};

    for (int base = 0; base < cnt; base += 8) {
        const int j = base + eg;
        const int sn = (j < deg) ? csr_src[e0 + j] : d;   // pad & self-loop -> d
        const uint4 g = *(const uint4*)(xl + (size_t)sn * 256 + w * 64 + cg * 8);
        float xv[8];
        xv[0] = __uint_as_float(g.x << 16);
        xv[1] = __uint_as_float(g.x & 0xffff0000u);
        xv[2] = __uint_as_float(g.y << 16);
        xv[3] = __uint_as_float(g.y & 0xffff0000u);
        xv[4] = __uint_as_float(g.z << 16);
        xv[5] = __uint_as_float(g.z & 0xffff0000u);
        xv[6] = __uint_as_float(g.w << 16);
        xv[7] = __uint_as_float(g.w & 0xffff0000u);
        float sc = 0.f;
#pragma unroll
        for (int i = 0; i < 8; ++i) {
            float v = xv[i] + xrv[i];
            v = fmaxf(v, NEG_SLOPE * v);     // leaky relu (slope<1)
            sc = fmaf(v, av[i], sc);
        }
        // reduce over channel groups (within 8-lane group)
        sc += __shfl_xor(sc, 1, 64);
        sc += __shfl_xor(sc, 2, 64);
        sc += __shfl_xor(sc, 4, 64);         // lane now holds full score of edge j
        sc = (j < cnt) ? sc : -INFINITY;     // mask pad edges
        // chunk max across the 8 edge slots -> uniform
        float mx = fmaxf(sc, __shfl_xor(sc, 8, 64));
        mx = fmaxf(mx, __shfl_xor(mx, 16, 64));
        mx = fmaxf(mx, __shfl_xor(mx, 32, 64));
        if (mx > m) {
            const float g2 = __expf(m - mx); // m==-inf -> 0
            s_loc *= g2;
#pragma unroll
            for (int i = 0; i < 8; ++i) acc8[i] *= g2;
            m = mx;
        }
        const float p = __expf(sc - m);      // pad -> exp(-inf)=0
        s_loc += p;
#pragma unroll
        for (int i = 0; i < 8; ++i) acc8[i] = fmaf(p, xv[i], acc8[i]);
    }

    // reduce across edge slots (once per node)
    float s_tot = s_loc;
    s_tot += __shfl_xor(s_tot, 8, 64);
    s_tot += __shfl_xor(s_tot, 16, 64);
    s_tot += __shfl_xor(s_tot, 32, 64);
#pragma unroll
    for (int i = 0; i < 8; ++i) {
        acc8[i] += __shfl_xor(acc8[i], 8, 64);
        acc8[i] += __shfl_xor(acc8[i], 16, 64);
        acc8[i] += __shfl_xor(acc8[i], 32, 64);
    }
    const float inv_s = 1.f / s_tot;
    float o8[8];
    const float* bp = bias + w * 64 + cg * 8;
#pragma unroll
    for (int i = 0; i < 8; ++i) o8[i] = acc8[i] * inv_s + bp[i];

    if (apply_elu) {
#pragma unroll
        for (int i = 0; i < 8; ++i) o8[i] = o8[i] > 0.f ? o8[i] : expm1f(o8[i]);
        if (eg == 0) {
            float* op = out + (size_t)d * 256 + w * 64 + cg * 8;
            *(float4*)op       = make_float4(o8[0], o8[1], o8[2], o8[3]);
            *(float4*)(op + 4) = make_float4(o8[4], o8[5], o8[6], o8[7]);
        }
    } else {
        if (eg == 0) {
            float* op = out + (size_t)d * 256 + w * 64 + cg * 8;
            *(float4*)op       = make_float4(o8[0], o8[1], o8[2], o8[3]);
            *(float4*)(op + 4) = make_float4(o8[4], o8[5], o8[6], o8[7]);
        }
        // fused row log_softmax over 256 (values replicated across edge groups)
        float mx = o8[0];
#pragma unroll
        for (int i = 1; i < 8; ++i) mx = fmaxf(mx, o8[i]);
        mx = fmaxf(mx, __shfl_xor(mx, 1, 64));
        mx = fmaxf(mx, __shfl_xor(mx, 2, 64));
        mx = fmaxf(mx, __shfl_xor(mx, 4, 64));
        if (lane == 0) red[w] = mx;
        __syncthreads();
        const float m4 = fmaxf(fmaxf(red[0], red[1]), fmaxf(red[2], red[3]));
        float se = 0.f;
#pragma unroll
        for (int i = 0; i < 8; ++i) se += __expf(o8[i] - m4);
        se += __shfl_xor(se, 1, 64);
        se += __shfl_xor(se, 2, 64);
        se += __shfl_xor(se, 4, 64);
        if (lane == 0) red[4 + w] = se;
        __syncthreads();
        const float s4 = (red[4] + red[5]) + (red[6] + red[7]);
        const float lg = m4 + logf(s4);
        if (eg == 0) {
            float* lp = out_ls + (size_t)d * 256 + w * 64 + cg * 8;
            *(float4*)lp       = make_float4(o8[0] - lg, o8[1] - lg, o8[2] - lg, o8[3] - lg);
            *(float4*)(lp + 4) = make_float4(o8[4] - lg, o8[5] - lg, o8[6] - lg, o8[7] - lg);
        }
    }
}

extern "C" void kernel_launch(void* const* d_in, const int* in_sizes, int n_in,
                              void* d_out, int out_size, void* d_ws, size_t ws_size,
                              hipStream_t stream) {
    const float* x     = (const float*)d_in[0];
    const int*   edge  = (const int*)d_in[1];
    const float* Wl1   = (const float*)d_in[2];
    const float* bl1   = (const float*)d_in[3];
    const float* Wr1   = (const float*)d_in[4];
    const float* br1   = (const float*)d_in[5];
    const float* att1  = (const float*)d_in[6];
    const float* bias1 = (const float*)d_in[7];
    const float* Wl2   = (const float*)d_in[8];
    const float* bl2   = (const float*)d_in[9];
    const float* Wr2   = (const float*)d_in[10];
    const float* br2   = (const float*)d_in[11];
    const float* att2  = (const float*)d_in[12];
    const float* bias2 = (const float*)d_in[13];

    const int N = in_sizes[0] / 64;  // 20000
    const int E = in_sizes[1] / 2;   // 500000
    const int* srcI = edge;
    const int* dstI = edge + E;

    const size_t NM = (size_t)N * 256;
    float*    XR  = (float*)d_ws;             // NM floats (xr, fp32)
    float*    C   = XR + NM;                  // NM floats (layer-1 out)
    ushort_t* XLB = (ushort_t*)(C + NM);      // NM ushorts (xl, bf16)
    int* deg     = (int*)(XLB + NM);          // N
    int* row_ptr = deg + N;                   // N+1
    int* cursor  = row_ptr + N + 1;           // N
    int* partial = cursor + N;                // nb
    int* blk_off = partial + ((N + 255) / 256);      // nb+1
    int* csr_src = blk_off + ((N + 255) / 256) + 1;  // E

    const int nb = (N + 255) / 256;
    const int e_grid = (E + 255) / 256;
    const dim3 gemm_grid((N + 127) / 128, 2);

    // ---- CSR by destination ----
    hipMemsetAsync(deg, 0, (size_t)N * sizeof(int), stream);
    hipMemsetAsync(cursor, 0, (size_t)N * sizeof(int), stream);
    hist_kernel<<<e_grid, 256, 0, stream>>>(dstI, deg, E);
    partial_kernel<<<nb, 256, 0, stream>>>(deg, partial, N);
    scan_kernel<<<1, 1024, 0, stream>>>(partial, blk_off, nb);
    scan_block_kernel<<<nb, 256, 0, stream>>>(deg, blk_off, row_ptr, N);
    scatter_kernel<<<e_grid, 256, 0, stream>>>(srcI, dstI, row_ptr, cursor, csr_src, E);

    // ---- layer 1 ----
    gemm128_kernel<64, true><<<gemm_grid, 256, 0, stream>>>(x, Wl1, bl1, XLB, N);
    gemm128_kernel<64, false><<<gemm_grid, 256, 0, stream>>>(x, Wr1, br1, XR, N);
    gat_fused_kernel<<<N, 256, 0, stream>>>(csr_src, row_ptr, XLB, XR, att1, bias1,
                                            C, nullptr, N, 1);

    // ---- layer 2 ----
    gemm128_kernel<256, true><<<gemm_grid, 256, 0, stream>>>(C, Wl2, bl2, XLB, N);
    gemm128_kernel<256, false><<<gemm_grid, 256, 0, stream>>>(C, Wr2, br2, XR, N);
    float* h2 = (float*)d_out;
    gat_fused_kernel<<<N, 256, 0, stream>>>(csr_src, row_ptr, XLB, XR, att2, bias2,
                                            h2, h2 + NM, N, 0);
}

// Round 6
// 310.779 us; speedup vs baseline: 7.0059x; 1.2023x over previous
//
#include <hip/hip_runtime.h>
#include <math.h>

#define NEG_SLOPE 0.2f

typedef unsigned short ushort_t;
typedef __attribute__((ext_vector_type(8))) short short8;
typedef __attribute__((ext_vector_type(4))) float float4v;

__device__ __forceinline__ ushort_t f2bf(float f) {           // RNE
    unsigned u = __float_as_uint(f);
    return (ushort_t)((u + 0x7fffu + ((u >> 16) & 1u)) >> 16);
}
__device__ __forceinline__ unsigned pack2bf(float lo, float hi) {
    return ((unsigned)f2bf(hi) << 16) | (unsigned)f2bf(lo);
}

// ================= CSR build =================
__global__ void hist_kernel(const int* __restrict__ dst, int* __restrict__ deg, int E) {
    int i = blockIdx.x * 256 + threadIdx.x;
    if (i < E) atomicAdd(&deg[dst[i]], 1);
}

__global__ void partial_kernel(const int* __restrict__ deg, int* __restrict__ partial, int n) {
    const int t = threadIdx.x;
    const int i = blockIdx.x * 256 + t;
    int v = (i < n) ? deg[i] : 0;
#pragma unroll
    for (int off = 32; off > 0; off >>= 1) v += __shfl_xor(v, off, 64);
    __shared__ int ws[4];
    if ((t & 63) == 0) ws[t >> 6] = v;
    __syncthreads();
    if (t == 0) partial[blockIdx.x] = ws[0] + ws[1] + ws[2] + ws[3];
}

__global__ void scan_kernel(const int* __restrict__ in, int* __restrict__ out, int n) {
    __shared__ int sm[1024];
    __shared__ int carry_s;
    const int t = threadIdx.x;
    if (t == 0) { carry_s = 0; out[0] = 0; }
    __syncthreads();
    for (int base = 0; base < n; base += 1024) {
        int v = (base + t < n) ? in[base + t] : 0;
        sm[t] = v;
        __syncthreads();
        for (int off = 1; off < 1024; off <<= 1) {
            int u = (t >= off) ? sm[t - off] : 0;
            __syncthreads();
            sm[t] += u;
            __syncthreads();
        }
        if (base + t < n) out[base + t + 1] = carry_s + sm[t];
        __syncthreads();
        if (t == 0) carry_s += sm[1023];
        __syncthreads();
    }
}

__global__ void scan_block_kernel(const int* __restrict__ deg, const int* __restrict__ blk_off,
                                  int* __restrict__ row_ptr, int n) {
    const int t = threadIdx.x;
    const int i = blockIdx.x * 256 + t;
    const int lane = t & 63, w = t >> 6;
    int x = (i < n) ? deg[i] : 0;
#pragma unroll
    for (int off = 1; off < 64; off <<= 1) {
        int u = __shfl_up(x, off, 64);
        if (lane >= off) x += u;
    }
    __shared__ int ws[4];
    if (lane == 63) ws[w] = x;
    __syncthreads();
    int add = blk_off[blockIdx.x];
#pragma unroll
    for (int j = 0; j < 4; ++j)
        if (j < w) add += ws[j];
    if (i < n) row_ptr[i + 1] = add + x;
    if (i == 0) row_ptr[0] = 0;
}

__global__ void scatter_kernel(const int* __restrict__ src, const int* __restrict__ dst,
                               const int* __restrict__ row_ptr, int* __restrict__ cursor,
                               int* __restrict__ csr_src, int E) {
    int i = blockIdx.x * 256 + threadIdx.x;
    if (i < E) {
        int d = dst[i];
        int pos = row_ptr[d] + atomicAdd(&cursor[d], 1);
        csr_src[pos] = src[i];
    }
}

// ================= weight transpose+bf16: WT[c][k] = bf16(W[k][c]) =================
__global__ void wt_bf16_kernel(const float* __restrict__ W, ushort_t* __restrict__ WT, int K) {
    int idx = blockIdx.x * 256 + threadIdx.x;   // = k*256 + c
    if (idx < K * 256) {
        int k = idx >> 8, c = idx & 255;
        WT[(size_t)c * K + k] = f2bf(W[idx]);
    }
}

// ================= MFMA bf16 GEMM: out[M,256] = A[M,K] @ W[K,256] + b =================
// A: fp32 (A_FP32) or bf16 row-major [M,K]; BT: bf16 [256][K] (= W^T).
// Tile 128x128, 4 waves (2x2), each wave 64x64 via 4x4 fragments of 16x16x32.
template <int K, bool A_FP32, bool OUT_BF16>
__global__ __launch_bounds__(256) void gemm_mfma_kernel(const void* __restrict__ Av,
                                                        const ushort_t* __restrict__ BT,
                                                        const float* __restrict__ bias,
                                                        void* __restrict__ outv, int M) {
    __shared__ ushort_t As[128][40];   // [row][k], pad 40 (80B stride, 16B-aligned)
    __shared__ ushort_t Bs[128][40];   // [col][k]
    const int t = threadIdx.x;
    const int row0 = blockIdx.x * 128, col0 = blockIdx.y * 128;
    const int wid = t >> 6, lane = t & 63;
    const int wr = wid >> 1, wc = wid & 1;
    const int frow = lane & 15, fk = (lane >> 4) * 8;
    const int srow = t >> 1, sks = (t & 1) * 16;   // staging: row/col, k-offset

    float4v acc[4][4];
#pragma unroll
    for (int i = 0; i < 4; ++i)
#pragma unroll
        for (int j = 0; j < 4; ++j) acc[i][j] = (float4v){0.f, 0.f, 0.f, 0.f};

    for (int k0 = 0; k0 < K; k0 += 32) {
        // ---- stage A (convert fp32->bf16 if needed) ----
        uint4 va0 = make_uint4(0, 0, 0, 0), va1 = va0;
        if (row0 + srow < M) {
            if (A_FP32) {
                const float* Xf = (const float*)Av + (size_t)(row0 + srow) * K + k0 + sks;
                float4 x0 = *(const float4*)(Xf + 0);
                float4 x1 = *(const float4*)(Xf + 4);
                float4 x2 = *(const float4*)(Xf + 8);
                float4 x3 = *(const float4*)(Xf + 12);
                va0 = make_uint4(pack2bf(x0.x, x0.y), pack2bf(x0.z, x0.w),
                                 pack2bf(x1.x, x1.y), pack2bf(x1.z, x1.w));
                va1 = make_uint4(pack2bf(x2.x, x2.y), pack2bf(x2.z, x2.w),
                                 pack2bf(x3.x, x3.y), pack2bf(x3.z, x3.w));
            } else {
                const ushort_t* Xb = (const ushort_t*)Av + (size_t)(row0 + srow) * K + k0 + sks;
                va0 = *(const uint4*)(Xb + 0);
                va1 = *(const uint4*)(Xb + 8);
            }
        }
        *(uint4*)&As[srow][sks + 0] = va0;
        *(uint4*)&As[srow][sks + 8] = va1;
        // ---- stage B from BT (bf16 direct) ----
        {
            const ushort_t* Bp = BT + (size_t)(col0 + srow) * K + k0 + sks;
            *(uint4*)&Bs[srow][sks + 0] = *(const uint4*)(Bp + 0);
            *(uint4*)&Bs[srow][sks + 8] = *(const uint4*)(Bp + 8);
        }
        __syncthreads();
        short8 af[4], bf[4];
#pragma unroll
        for (int mi = 0; mi < 4; ++mi)
            af[mi] = *(const short8*)&As[wr * 64 + mi * 16 + frow][fk];
#pragma unroll
        for (int ni = 0; ni < 4; ++ni)
            bf[ni] = *(const short8*)&Bs[wc * 64 + ni * 16 + frow][fk];
#pragma unroll
        for (int mi = 0; mi < 4; ++mi)
#pragma unroll
            for (int ni = 0; ni < 4; ++ni)
                acc[mi][ni] = __builtin_amdgcn_mfma_f32_16x16x32_bf16(af[mi], bf[ni],
                                                                     acc[mi][ni], 0, 0, 0);
        __syncthreads();
    }

    // ---- epilogue: C/D layout col=lane&15, row=(lane>>4)*4+reg ----
    const int crow = (lane >> 4) * 4;
#pragma unroll
    for (int ni = 0; ni < 4; ++ni) {
        const int col = col0 + wc * 64 + ni * 16 + frow;
        const float bv = bias[col];
#pragma unroll
        for (int mi = 0; mi < 4; ++mi) {
#pragma unroll
            for (int r = 0; r < 4; ++r) {
                const int row = row0 + wr * 64 + mi * 16 + crow + r;
                if (row < M) {
                    const float v = acc[mi][ni][r] + bv;
                    if (OUT_BF16) ((ushort_t*)outv)[(size_t)row * 256 + col] = f2bf(v);
                    else          ((float*)outv)[(size_t)row * 256 + col] = v;
                }
            }
        }
    }
}

// ================= fused GAT, lane = (edge_slot, channel_group) =================
__global__ __launch_bounds__(256) void gat_fused_kernel(const int* __restrict__ csr_src,
                                                        const int* __restrict__ row_ptr,
                                                        const ushort_t* __restrict__ xl,
                                                        const float* __restrict__ xr,
                                                        const float* __restrict__ att,
                                                        const float* __restrict__ bias,
                                                        ushort_t* __restrict__ out_b,
                                                        float* __restrict__ out,
                                                        float* __restrict__ out_ls,
                                                        int n_nodes, int apply_elu) {
    __shared__ float red[8];
    const int d = blockIdx.x;
    const int t = threadIdx.x;
    const int w = t >> 6;            // head
    const int lane = t & 63;
    const int eg = lane >> 3;        // edge slot 0..7
    const int cg = lane & 7;         // channel group 0..7

    float xrv[8], av[8];
    {
        const float* xrp = xr + (size_t)d * 256 + w * 64 + cg * 8;
        const float* ap  = att + w * 64 + cg * 8;
        *(float4*)&xrv[0] = *(const float4*)xrp;
        *(float4*)&xrv[4] = *(const float4*)(xrp + 4);
        *(float4*)&av[0]  = *(const float4*)ap;
        *(float4*)&av[4]  = *(const float4*)(ap + 4);
    }
    const int e0 = row_ptr[d];
    const int deg = row_ptr[d + 1] - e0;
    const int cnt = deg + 1;         // + self loop at index deg
    float m = -INFINITY, s_loc = 0.f;
    float acc8[8] = {0.f, 0.f, 0.f, 0.f, 0.f, 0.f, 0.f, 0.f};

    for (int base = 0; base < cnt; base += 8) {
        const int j = base + eg;
        const int sn = (j < deg) ? csr_src[e0 + j] : d;   // pad & self-loop -> d
        const uint4 g = *(const uint4*)(xl + (size_t)sn * 256 + w * 64 + cg * 8);
        float xv[8];
        xv[0] = __uint_as_float(g.x << 16);
        xv[1] = __uint_as_float(g.x & 0xffff0000u);
        xv[2] = __uint_as_float(g.y << 16);
        xv[3] = __uint_as_float(g.y & 0xffff0000u);
        xv[4] = __uint_as_float(g.z << 16);
        xv[5] = __uint_as_float(g.z & 0xffff0000u);
        xv[6] = __uint_as_float(g.w << 16);
        xv[7] = __uint_as_float(g.w & 0xffff0000u);
        float sc = 0.f;
#pragma unroll
        for (int i = 0; i < 8; ++i) {
            float v = xv[i] + xrv[i];
            v = fmaxf(v, NEG_SLOPE * v);     // leaky relu (slope<1)
            sc = fmaf(v, av[i], sc);
        }
        sc += __shfl_xor(sc, 1, 64);
        sc += __shfl_xor(sc, 2, 64);
        sc += __shfl_xor(sc, 4, 64);         // lane holds full score of edge j
        sc = (j < cnt) ? sc : -INFINITY;     // mask pad edges
        float mx = fmaxf(sc, __shfl_xor(sc, 8, 64));
        mx = fmaxf(mx, __shfl_xor(mx, 16, 64));
        mx = fmaxf(mx, __shfl_xor(mx, 32, 64));
        if (mx > m) {
            const float g2 = __expf(m - mx); // m==-inf -> 0
            s_loc *= g2;
#pragma unroll
            for (int i = 0; i < 8; ++i) acc8[i] *= g2;
            m = mx;
        }
        const float p = __expf(sc - m);      // pad -> exp(-inf)=0
        s_loc += p;
#pragma unroll
        for (int i = 0; i < 8; ++i) acc8[i] = fmaf(p, xv[i], acc8[i]);
    }

    float s_tot = s_loc;
    s_tot += __shfl_xor(s_tot, 8, 64);
    s_tot += __shfl_xor(s_tot, 16, 64);
    s_tot += __shfl_xor(s_tot, 32, 64);
#pragma unroll
    for (int i = 0; i < 8; ++i) {
        acc8[i] += __shfl_xor(acc8[i], 8, 64);
        acc8[i] += __shfl_xor(acc8[i], 16, 64);
        acc8[i] += __shfl_xor(acc8[i], 32, 64);
    }
    const float inv_s = 1.f / s_tot;
    float o8[8];
    const float* bp = bias + w * 64 + cg * 8;
#pragma unroll
    for (int i = 0; i < 8; ++i) o8[i] = acc8[i] * inv_s + bp[i];

    if (apply_elu) {
#pragma unroll
        for (int i = 0; i < 8; ++i) o8[i] = o8[i] > 0.f ? o8[i] : expm1f(o8[i]);
        if (eg == 0) {
            uint4 u;
            u.x = pack2bf(o8[0], o8[1]);
            u.y = pack2bf(o8[2], o8[3]);
            u.z = pack2bf(o8[4], o8[5]);
            u.w = pack2bf(o8[6], o8[7]);
            *(uint4*)(out_b + (size_t)d * 256 + w * 64 + cg * 8) = u;
        }
    } else {
        if (eg == 0) {
            float* op = out + (size_t)d * 256 + w * 64 + cg * 8;
            *(float4*)op       = make_float4(o8[0], o8[1], o8[2], o8[3]);
            *(float4*)(op + 4) = make_float4(o8[4], o8[5], o8[6], o8[7]);
        }
        // fused row log_softmax over 256 (values replicated across edge groups)
        float mx = o8[0];
#pragma unroll
        for (int i = 1; i < 8; ++i) mx = fmaxf(mx, o8[i]);
        mx = fmaxf(mx, __shfl_xor(mx, 1, 64));
        mx = fmaxf(mx, __shfl_xor(mx, 2, 64));
        mx = fmaxf(mx, __shfl_xor(mx, 4, 64));
        if (lane == 0) red[w] = mx;
        __syncthreads();
        const float m4 = fmaxf(fmaxf(red[0], red[1]), fmaxf(red[2], red[3]));
        float se = 0.f;
#pragma unroll
        for (int i = 0; i < 8; ++i) se += __expf(o8[i] - m4);
        se += __shfl_xor(se, 1, 64);
        se += __shfl_xor(se, 2, 64);
        se += __shfl_xor(se, 4, 64);
        if (lane == 0) red[4 + w] = se;
        __syncthreads();
        const float s4 = (red[4] + red[5]) + (red[6] + red[7]);
        const float lg = m4 + logf(s4);
        if (eg == 0) {
            float* lp = out_ls + (size_t)d * 256 + w * 64 + cg * 8;
            *(float4*)lp       = make_float4(o8[0] - lg, o8[1] - lg, o8[2] - lg, o8[3] - lg);
            *(float4*)(lp + 4) = make_float4(o8[4] - lg, o8[5] - lg, o8[6] - lg, o8[7] - lg);
        }
    }
}

extern "C" void kernel_launch(void* const* d_in, const int* in_sizes, int n_in,
                              void* d_out, int out_size, void* d_ws, size_t ws_size,
                              hipStream_t stream) {
    const float* x     = (const float*)d_in[0];
    const int*   edge  = (const int*)d_in[1];
    const float* Wl1   = (const float*)d_in[2];
    const float* bl1   = (const float*)d_in[3];
    const float* Wr1   = (const float*)d_in[4];
    const float* br1   = (const float*)d_in[5];
    const float* att1  = (const float*)d_in[6];
    const float* bias1 = (const float*)d_in[7];
    const float* Wl2   = (const float*)d_in[8];
    const float* bl2   = (const float*)d_in[9];
    const float* Wr2   = (const float*)d_in[10];
    const float* br2   = (const float*)d_in[11];
    const float* att2  = (const float*)d_in[12];
    const float* bias2 = (const float*)d_in[13];

    const int N = in_sizes[0] / 64;  // 20000
    const int E = in_sizes[1] / 2;   // 500000
    const int* srcI = edge;
    const int* dstI = edge + E;

    const size_t NM = (size_t)N * 256;
    float*    XR   = (float*)d_ws;                 // NM fp32 (xr)
    ushort_t* XB   = (ushort_t*)(XR + NM);         // NM bf16 (layer-1 out = layer-2 in)
    ushort_t* XLB  = XB + NM;                      // NM bf16 (xl gather table)
    ushort_t* WT1l = XLB + NM;                     // 256*64
    ushort_t* WT1r = WT1l + 256 * 64;              // 256*64
    ushort_t* WT2l = WT1r + 256 * 64;              // 256*256
    ushort_t* WT2r = WT2l + 256 * 256;             // 256*256
    int* deg     = (int*)(WT2r + 256 * 256);       // N
    int* row_ptr = deg + N;                        // N+1
    int* cursor  = row_ptr + N + 1;                // N
    int* partial = cursor + N;                     // nb
    int* blk_off = partial + ((N + 255) / 256);      // nb+1
    int* csr_src = blk_off + ((N + 255) / 256) + 1;  // E

    const int nb = (N + 255) / 256;
    const int e_grid = (E + 255) / 256;
    const dim3 gemm_grid((N + 127) / 128, 2);

    // ---- weight transposes to bf16 (tiny) ----
    wt_bf16_kernel<<<64, 256, 0, stream>>>(Wl1, WT1l, 64);
    wt_bf16_kernel<<<64, 256, 0, stream>>>(Wr1, WT1r, 64);
    wt_bf16_kernel<<<256, 256, 0, stream>>>(Wl2, WT2l, 256);
    wt_bf16_kernel<<<256, 256, 0, stream>>>(Wr2, WT2r, 256);

    // ---- CSR by destination ----
    hipMemsetAsync(deg, 0, (size_t)N * sizeof(int), stream);
    hipMemsetAsync(cursor, 0, (size_t)N * sizeof(int), stream);
    hist_kernel<<<e_grid, 256, 0, stream>>>(dstI, deg, E);
    partial_kernel<<<nb, 256, 0, stream>>>(deg, partial, N);
    scan_kernel<<<1, 1024, 0, stream>>>(partial, blk_off, nb);
    scan_block_kernel<<<nb, 256, 0, stream>>>(deg, blk_off, row_ptr, N);
    scatter_kernel<<<e_grid, 256, 0, stream>>>(srcI, dstI, row_ptr, cursor, csr_src, E);

    // ---- layer 1 (A = x fp32, K=64) ----
    gemm_mfma_kernel<64, true, true><<<gemm_grid, 256, 0, stream>>>(x, WT1l, bl1, XLB, N);
    gemm_mfma_kernel<64, true, false><<<gemm_grid, 256, 0, stream>>>(x, WT1r, br1, XR, N);
    gat_fused_kernel<<<N, 256, 0, stream>>>(csr_src, row_ptr, XLB, XR, att1, bias1,
                                            XB, nullptr, nullptr, N, 1);

    // ---- layer 2 (A = XB bf16, K=256) ----
    gemm_mfma_kernel<256, false, true><<<gemm_grid, 256, 0, stream>>>(XB, WT2l, bl2, XLB, N);
    gemm_mfma_kernel<256, false, false><<<gemm_grid, 256, 0, stream>>>(XB, WT2r, br2, XR, N);
    float* h2 = (float*)d_out;
    gat_fused_kernel<<<N, 256, 0, stream>>>(csr_src, row_ptr, XLB, XR, att2, bias2,
                                            nullptr, h2, h2 + NM, N, 0);
}

// Round 7
// 249.205 us; speedup vs baseline: 8.7370x; 1.2471x over previous
//
#include <hip/hip_runtime.h>
#include <math.h>

#define NEG_SLOPE 0.2f

typedef unsigned short ushort_t;
typedef __attribute__((ext_vector_type(8))) short short8;
typedef __attribute__((ext_vector_type(4))) float float4v;
typedef _Float16 half2v __attribute__((ext_vector_type(2)));

#if defined(__has_builtin)
#if __has_builtin(__builtin_amdgcn_fdot2)
#define HAS_FDOT2 1
#endif
#endif

__device__ __forceinline__ ushort_t f2bf(float f) {           // RNE
    unsigned u = __float_as_uint(f);
    return (ushort_t)((u + 0x7fffu + ((u >> 16) & 1u)) >> 16);
}
__device__ __forceinline__ unsigned pack2bf(float lo, float hi) {
    return ((unsigned)f2bf(hi) << 16) | (unsigned)f2bf(lo);
}

// ================= CSR build =================
__global__ void hist_kernel(const int* __restrict__ dst, int* __restrict__ deg, int E) {
    int i = blockIdx.x * 256 + threadIdx.x;
    if (i < E) atomicAdd(&deg[dst[i]], 1);
}

__global__ void partial_kernel(const int* __restrict__ deg, int* __restrict__ partial, int n) {
    const int t = threadIdx.x;
    const int i = blockIdx.x * 256 + t;
    int v = (i < n) ? deg[i] : 0;
#pragma unroll
    for (int off = 32; off > 0; off >>= 1) v += __shfl_xor(v, off, 64);
    __shared__ int ws[4];
    if ((t & 63) == 0) ws[t >> 6] = v;
    __syncthreads();
    if (t == 0) partial[blockIdx.x] = ws[0] + ws[1] + ws[2] + ws[3];
}

__global__ void scan_kernel(const int* __restrict__ in, int* __restrict__ out, int n) {
    __shared__ int sm[1024];
    __shared__ int carry_s;
    const int t = threadIdx.x;
    if (t == 0) { carry_s = 0; out[0] = 0; }
    __syncthreads();
    for (int base = 0; base < n; base += 1024) {
        int v = (base + t < n) ? in[base + t] : 0;
        sm[t] = v;
        __syncthreads();
        for (int off = 1; off < 1024; off <<= 1) {
            int u = (t >= off) ? sm[t - off] : 0;
            __syncthreads();
            sm[t] += u;
            __syncthreads();
        }
        if (base + t < n) out[base + t + 1] = carry_s + sm[t];
        __syncthreads();
        if (t == 0) carry_s += sm[1023];
        __syncthreads();
    }
}

__global__ void scan_block_kernel(const int* __restrict__ deg, const int* __restrict__ blk_off,
                                  int* __restrict__ row_ptr, int n) {
    const int t = threadIdx.x;
    const int i = blockIdx.x * 256 + t;
    const int lane = t & 63, w = t >> 6;
    int x = (i < n) ? deg[i] : 0;
#pragma unroll
    for (int off = 1; off < 64; off <<= 1) {
        int u = __shfl_up(x, off, 64);
        if (lane >= off) x += u;
    }
    __shared__ int ws[4];
    if (lane == 63) ws[w] = x;
    __syncthreads();
    int add = blk_off[blockIdx.x];
#pragma unroll
    for (int j = 0; j < 4; ++j)
        if (j < w) add += ws[j];
    if (i < n) row_ptr[i + 1] = add + x;
    if (i == 0) row_ptr[0] = 0;
}

__global__ void scatter_kernel(const int* __restrict__ src, const int* __restrict__ dst,
                               const int* __restrict__ row_ptr, int* __restrict__ cursor,
                               int* __restrict__ csr_src, int E) {
    int i = blockIdx.x * 256 + threadIdx.x;
    if (i < E) {
        int d = dst[i];
        int pos = row_ptr[d] + atomicAdd(&cursor[d], 1);
        csr_src[pos] = src[i];
    }
}

// ================= weight transpose+bf16: WT[c][k] = bf16(W[k][c]) =================
__global__ void wt_bf16_kernel(const float* __restrict__ W, ushort_t* __restrict__ WT, int K) {
    int idx = blockIdx.x * 256 + threadIdx.x;   // = k*256 + c
    if (idx < K * 256) {
        int k = idx >> 8, c = idx & 255;
        WT[(size_t)c * K + k] = f2bf(W[idx]);
    }
}

// ================= dual MFMA GEMM: outl = A@Wl+bl (fp16), outr = A@Wr+br (f32) ======
// A staged ONCE per tile for both weight matrices. Tile 64 rows x 128 cols,
// 4 waves (2x2): wave = 32 rows x 64 cols per matrix, frags 2x4 of 16x16x32 bf16.
template <int K, bool A_FP32>
__global__ __launch_bounds__(256) void gemm_dual_kernel(const void* __restrict__ Av,
                                                        const ushort_t* __restrict__ BTl,
                                                        const ushort_t* __restrict__ BTr,
                                                        const float* __restrict__ bl,
                                                        const float* __restrict__ br,
                                                        _Float16* __restrict__ outl,
                                                        float* __restrict__ outr, int M) {
    __shared__ ushort_t As[64][40];       // [row][k], pad->80B stride
    __shared__ ushort_t Bs[2][128][40];   // [mat][col][k]
    const int t = threadIdx.x;
    const int row0 = blockIdx.x * 64, col0 = blockIdx.y * 128;
    const int wid = t >> 6, lane = t & 63;
    const int wr = wid >> 1, wc = wid & 1;
    const int frow = lane & 15, fk = (lane >> 4) * 8;
    const int arow = t >> 2, ak8 = (t & 3) * 8;    // A staging: 64x32, 8 bf16/thread
    const int srow = t >> 1, sks = (t & 1) * 16;   // B staging: 128x32, 16 bf16/thread

    float4v acc[2][2][4];
#pragma unroll
    for (int m = 0; m < 2; ++m)
#pragma unroll
        for (int i = 0; i < 2; ++i)
#pragma unroll
            for (int j = 0; j < 4; ++j) acc[m][i][j] = (float4v){0.f, 0.f, 0.f, 0.f};

    for (int k0 = 0; k0 < K; k0 += 32) {
        uint4 va = make_uint4(0, 0, 0, 0);
        if (row0 + arow < M) {
            if (A_FP32) {
                const float* Xf = (const float*)Av + (size_t)(row0 + arow) * K + k0 + ak8;
                float4 x0 = *(const float4*)(Xf + 0);
                float4 x1 = *(const float4*)(Xf + 4);
                va = make_uint4(pack2bf(x0.x, x0.y), pack2bf(x0.z, x0.w),
                                pack2bf(x1.x, x1.y), pack2bf(x1.z, x1.w));
            } else {
                va = *(const uint4*)((const ushort_t*)Av + (size_t)(row0 + arow) * K + k0 + ak8);
            }
        }
        *(uint4*)&As[arow][ak8] = va;
        {
            const ushort_t* Bp = BTl + (size_t)(col0 + srow) * K + k0 + sks;
            *(uint4*)&Bs[0][srow][sks + 0] = *(const uint4*)(Bp + 0);
            *(uint4*)&Bs[0][srow][sks + 8] = *(const uint4*)(Bp + 8);
            const ushort_t* Bq = BTr + (size_t)(col0 + srow) * K + k0 + sks;
            *(uint4*)&Bs[1][srow][sks + 0] = *(const uint4*)(Bq + 0);
            *(uint4*)&Bs[1][srow][sks + 8] = *(const uint4*)(Bq + 8);
        }
        __syncthreads();
        short8 af[2], bf[2][4];
#pragma unroll
        for (int mi = 0; mi < 2; ++mi)
            af[mi] = *(const short8*)&As[wr * 32 + mi * 16 + frow][fk];
#pragma unroll
        for (int m = 0; m < 2; ++m)
#pragma unroll
            for (int ni = 0; ni < 4; ++ni)
                bf[m][ni] = *(const short8*)&Bs[m][wc * 64 + ni * 16 + frow][fk];
#pragma unroll
        for (int m = 0; m < 2; ++m)
#pragma unroll
            for (int mi = 0; mi < 2; ++mi)
#pragma unroll
                for (int ni = 0; ni < 4; ++ni)
                    acc[m][mi][ni] = __builtin_amdgcn_mfma_f32_16x16x32_bf16(
                        af[mi], bf[m][ni], acc[m][mi][ni], 0, 0, 0);
        __syncthreads();
    }

    // C/D layout: col=lane&15, row=(lane>>4)*4+reg  (verified mapping)
    const int crow = (lane >> 4) * 4;
#pragma unroll
    for (int ni = 0; ni < 4; ++ni) {
        const int col = col0 + wc * 64 + ni * 16 + frow;
        const float bvl = bl[col], bvr = br[col];
#pragma unroll
        for (int mi = 0; mi < 2; ++mi) {
#pragma unroll
            for (int r = 0; r < 4; ++r) {
                const int row = row0 + wr * 32 + mi * 16 + crow + r;
                if (row < M) {
                    outl[(size_t)row * 256 + col] = (_Float16)(acc[0][mi][ni][r] + bvl);
                    outr[(size_t)row * 256 + col] = acc[1][mi][ni][r] + bvr;
                }
            }
        }
    }
}

// ================= fused GAT, lane = (edge_slot, channel_group), fp16 gathers ========
__global__ __launch_bounds__(256) void gat_fused_kernel(const int* __restrict__ csr_src,
                                                        const int* __restrict__ row_ptr,
                                                        const _Float16* __restrict__ xl,
                                                        const float* __restrict__ xr,
                                                        const float* __restrict__ att,
                                                        const float* __restrict__ bias,
                                                        ushort_t* __restrict__ out_b,
                                                        float* __restrict__ out,
                                                        float* __restrict__ out_ls,
                                                        int n_nodes, int apply_elu) {
    __shared__ float red[8];
    const int d = blockIdx.x;
    const int t = threadIdx.x;
    const int w = t >> 6;            // head
    const int lane = t & 63;
    const int eg = lane >> 3;        // edge slot 0..7
    const int cg = lane & 7;         // channel group 0..7

    float xrf[8], avf[8];
    {
        const float* xrp = xr + (size_t)d * 256 + w * 64 + cg * 8;
        const float* ap  = att + w * 64 + cg * 8;
        *(float4*)&xrf[0] = *(const float4*)xrp;
        *(float4*)&xrf[4] = *(const float4*)(xrp + 4);
        *(float4*)&avf[0] = *(const float4*)ap;
        *(float4*)&avf[4] = *(const float4*)(ap + 4);
    }
#if HAS_FDOT2
    half2v xr2[4], a06[4], a04[4];   // lrelu(v)*a = (0.6a)*v + (0.4a)*|v|
#pragma unroll
    for (int i = 0; i < 4; ++i) {
        xr2[i] = (half2v){(_Float16)xrf[2 * i], (_Float16)xrf[2 * i + 1]};
        a06[i] = (half2v){(_Float16)(0.6f * avf[2 * i]), (_Float16)(0.6f * avf[2 * i + 1])};
        a04[i] = (half2v){(_Float16)(0.4f * avf[2 * i]), (_Float16)(0.4f * avf[2 * i + 1])};
    }
#endif
    const int e0 = row_ptr[d];
    const int deg = row_ptr[d + 1] - e0;
    const int cnt = deg + 1;         // + self loop at index deg
    float m = -INFINITY, s_loc = 0.f;
    float acc8[8] = {0.f, 0.f, 0.f, 0.f, 0.f, 0.f, 0.f, 0.f};

    for (int base = 0; base < cnt; base += 8) {
        const int j = base + eg;
        const int sn = (j < deg) ? csr_src[e0 + j] : d;   // pad & self-loop -> d
        union { uint4 u; _Float16 h[8]; half2v h2[4]; } U;
        U.u = *(const uint4*)(xl + (size_t)sn * 256 + w * 64 + cg * 8);
        float xvf[8];
#pragma unroll
        for (int i = 0; i < 8; ++i) xvf[i] = (float)U.h[i];
        float sc = 0.f;
#if HAS_FDOT2
#pragma unroll
        for (int i = 0; i < 4; ++i) {
            half2v v = U.h2[i] + xr2[i];                      // v_pk_add_f16
            unsigned vb = __builtin_bit_cast(unsigned, v);
            half2v va = __builtin_bit_cast(half2v, vb & 0x7fff7fffu);  // packed |v|
            sc = __builtin_amdgcn_fdot2(v, a06[i], sc, false);
            sc = __builtin_amdgcn_fdot2(va, a04[i], sc, false);
        }
#else
#pragma unroll
        for (int i = 0; i < 8; ++i) {
            float v = xvf[i] + xrf[i];
            v = fmaxf(v, NEG_SLOPE * v);
            sc = fmaf(v, avf[i], sc);
        }
#endif
        sc += __shfl_xor(sc, 1, 64);
        sc += __shfl_xor(sc, 2, 64);
        sc += __shfl_xor(sc, 4, 64);         // lane holds full score of edge j
        sc = (j < cnt) ? sc : -INFINITY;     // mask pad edges
        float mx = fmaxf(sc, __shfl_xor(sc, 8, 64));
        mx = fmaxf(mx, __shfl_xor(mx, 16, 64));
        mx = fmaxf(mx, __shfl_xor(mx, 32, 64));
        if (mx > m + 8.f) {                  // defer-rescale: p bounded by e^8
            const float g2 = __expf(m - mx); // m==-inf -> 0
            s_loc *= g2;
#pragma unroll
            for (int i = 0; i < 8; ++i) acc8[i] *= g2;
            m = mx;
        }
        const float p = __expf(sc - m);      // pad -> exp(-inf)=0
        s_loc += p;
#pragma unroll
        for (int i = 0; i < 8; ++i) acc8[i] = fmaf(p, xvf[i], acc8[i]);
    }

    float s_tot = s_loc;
    s_tot += __shfl_xor(s_tot, 8, 64);
    s_tot += __shfl_xor(s_tot, 16, 64);
    s_tot += __shfl_xor(s_tot, 32, 64);
#pragma unroll
    for (int i = 0; i < 8; ++i) {
        acc8[i] += __shfl_xor(acc8[i], 8, 64);
        acc8[i] += __shfl_xor(acc8[i], 16, 64);
        acc8[i] += __shfl_xor(acc8[i], 32, 64);
    }
    const float inv_s = 1.f / s_tot;
    float o8[8];
    const float* bp = bias + w * 64 + cg * 8;
#pragma unroll
    for (int i = 0; i < 8; ++i) o8[i] = acc8[i] * inv_s + bp[i];

    if (apply_elu) {
#pragma unroll
        for (int i = 0; i < 8; ++i) o8[i] = o8[i] > 0.f ? o8[i] : (__expf(o8[i]) - 1.f);
        if (eg == 0) {
            uint4 u;
            u.x = pack2bf(o8[0], o8[1]);
            u.y = pack2bf(o8[2], o8[3]);
            u.z = pack2bf(o8[4], o8[5]);
            u.w = pack2bf(o8[6], o8[7]);
            *(uint4*)(out_b + (size_t)d * 256 + w * 64 + cg * 8) = u;
        }
    } else {
        if (eg == 0) {
            float* op = out + (size_t)d * 256 + w * 64 + cg * 8;
            *(float4*)op       = make_float4(o8[0], o8[1], o8[2], o8[3]);
            *(float4*)(op + 4) = make_float4(o8[4], o8[5], o8[6], o8[7]);
        }
        // fused row log_softmax over 256 (values replicated across edge groups)
        float mx = o8[0];
#pragma unroll
        for (int i = 1; i < 8; ++i) mx = fmaxf(mx, o8[i]);
        mx = fmaxf(mx, __shfl_xor(mx, 1, 64));
        mx = fmaxf(mx, __shfl_xor(mx, 2, 64));
        mx = fmaxf(mx, __shfl_xor(mx, 4, 64));
        if (lane == 0) red[w] = mx;
        __syncthreads();
        const float m4 = fmaxf(fmaxf(red[0], red[1]), fmaxf(red[2], red[3]));
        float se = 0.f;
#pragma unroll
        for (int i = 0; i < 8; ++i) se += __expf(o8[i] - m4);
        se += __shfl_xor(se, 1, 64);
        se += __shfl_xor(se, 2, 64);
        se += __shfl_xor(se, 4, 64);
        if (lane == 0) red[4 + w] = se;
        __syncthreads();
        const float s4 = (red[4] + red[5]) + (red[6] + red[7]);
        const float lg = m4 + __logf(s4);
        if (eg == 0) {
            float* lp = out_ls + (size_t)d * 256 + w * 64 + cg * 8;
            *(float4*)lp       = make_float4(o8[0] - lg, o8[1] - lg, o8[2] - lg, o8[3] - lg);
            *(float4*)(lp + 4) = make_float4(o8[4] - lg, o8[5] - lg, o8[6] - lg, o8[7] - lg);
        }
    }
}

extern "C" void kernel_launch(void* const* d_in, const int* in_sizes, int n_in,
                              void* d_out, int out_size, void* d_ws, size_t ws_size,
                              hipStream_t stream) {
    const float* x     = (const float*)d_in[0];
    const int*   edge  = (const int*)d_in[1];
    const float* Wl1   = (const float*)d_in[2];
    const float* bl1   = (const float*)d_in[3];
    const float* Wr1   = (const float*)d_in[4];
    const float* br1   = (const float*)d_in[5];
    const float* att1  = (const float*)d_in[6];
    const float* bias1 = (const float*)d_in[7];
    const float* Wl2   = (const float*)d_in[8];
    const float* bl2   = (const float*)d_in[9];
    const float* Wr2   = (const float*)d_in[10];
    const float* br2   = (const float*)d_in[11];
    const float* att2  = (const float*)d_in[12];
    const float* bias2 = (const float*)d_in[13];

    const int N = in_sizes[0] / 64;  // 20000
    const int E = in_sizes[1] / 2;   // 500000
    const int* srcI = edge;
    const int* dstI = edge + E;

    const size_t NM = (size_t)N * 256;
    float*     XR   = (float*)d_ws;                // NM fp32 (xr)
    ushort_t*  XB   = (ushort_t*)(XR + NM);        // NM bf16 (layer-1 out = layer-2 A)
    _Float16*  XL   = (_Float16*)(XB + NM);        // NM fp16 (xl gather table)
    ushort_t*  WT1l = (ushort_t*)(XL + NM);        // 256*64
    ushort_t*  WT1r = WT1l + 256 * 64;             // 256*64
    ushort_t*  WT2l = WT1r + 256 * 64;             // 256*256
    ushort_t*  WT2r = WT2l + 256 * 256;            // 256*256
    int* deg     = (int*)(WT2r + 256 * 256);       // N
    int* row_ptr = deg + N;                        // N+1
    int* cursor  = row_ptr + N + 1;                // N
    int* partial = cursor + N;                     // nb
    int* blk_off = partial + ((N + 255) / 256);      // nb+1
    int* csr_src = blk_off + ((N + 255) / 256) + 1;  // E

    const int nb = (N + 255) / 256;
    const int e_grid = (E + 255) / 256;
    const dim3 gemm_grid((N + 63) / 64, 2);

    // ---- weight transposes to bf16 (tiny) ----
    wt_bf16_kernel<<<64, 256, 0, stream>>>(Wl1, WT1l, 64);
    wt_bf16_kernel<<<64, 256, 0, stream>>>(Wr1, WT1r, 64);
    wt_bf16_kernel<<<256, 256, 0, stream>>>(Wl2, WT2l, 256);
    wt_bf16_kernel<<<256, 256, 0, stream>>>(Wr2, WT2r, 256);

    // ---- CSR by destination ----
    hipMemsetAsync(deg, 0, (size_t)N * sizeof(int), stream);
    hipMemsetAsync(cursor, 0, (size_t)N * sizeof(int), stream);
    hist_kernel<<<e_grid, 256, 0, stream>>>(dstI, deg, E);
    partial_kernel<<<nb, 256, 0, stream>>>(deg, partial, N);
    scan_kernel<<<1, 1024, 0, stream>>>(partial, blk_off, nb);
    scan_block_kernel<<<nb, 256, 0, stream>>>(deg, blk_off, row_ptr, N);
    scatter_kernel<<<e_grid, 256, 0, stream>>>(srcI, dstI, row_ptr, cursor, csr_src, E);

    // ---- layer 1 (A = x fp32, K=64): one dual GEMM -> XL (fp16) + XR (f32) ----
    gemm_dual_kernel<64, true><<<gemm_grid, 256, 0, stream>>>(x, WT1l, WT1r, bl1, br1,
                                                              XL, XR, N);
    gat_fused_kernel<<<N, 256, 0, stream>>>(csr_src, row_ptr, XL, XR, att1, bias1,
                                            XB, nullptr, nullptr, N, 1);

    // ---- layer 2 (A = XB bf16, K=256) ----
    gemm_dual_kernel<256, false><<<gemm_grid, 256, 0, stream>>>(XB, WT2l, WT2r, bl2, br2,
                                                                XL, XR, N);
    float* h2 = (float*)d_out;
    gat_fused_kernel<<<N, 256, 0, stream>>>(csr_src, row_ptr, XL, XR, att2, bias2,
                                            nullptr, h2, h2 + NM, N, 0);
}

// Round 8
// 235.210 us; speedup vs baseline: 9.2568x; 1.0595x over previous
//
#include <hip/hip_runtime.h>
#include <math.h>

#define NEG_SLOPE 0.2f

typedef unsigned short ushort_t;
typedef __attribute__((ext_vector_type(8))) short short8;
typedef __attribute__((ext_vector_type(4))) float float4v;
typedef _Float16 half2v __attribute__((ext_vector_type(2)));

#if defined(__has_builtin)
#if __has_builtin(__builtin_amdgcn_fdot2)
#define HAS_FDOT2 1
#endif
#endif

__device__ __forceinline__ ushort_t f2bf(float f) {           // RNE
    unsigned u = __float_as_uint(f);
    return (ushort_t)((u + 0x7fffu + ((u >> 16) & 1u)) >> 16);
}
__device__ __forceinline__ unsigned pack2bf(float lo, float hi) {
    return ((unsigned)f2bf(hi) << 16) | (unsigned)f2bf(lo);
}

// ================= CSR build =================
__global__ void hist_kernel(const int* __restrict__ dst, int* __restrict__ deg, int E) {
    int i = blockIdx.x * 256 + threadIdx.x;
    if (i < E) atomicAdd(&deg[dst[i]], 1);
}

__global__ void partial_kernel(const int* __restrict__ deg, int* __restrict__ partial, int n) {
    const int t = threadIdx.x;
    const int i = blockIdx.x * 256 + t;
    int v = (i < n) ? deg[i] : 0;
#pragma unroll
    for (int off = 32; off > 0; off >>= 1) v += __shfl_xor(v, off, 64);
    __shared__ int ws[4];
    if ((t & 63) == 0) ws[t >> 6] = v;
    __syncthreads();
    if (t == 0) partial[blockIdx.x] = ws[0] + ws[1] + ws[2] + ws[3];
}

__global__ void scan_kernel(const int* __restrict__ in, int* __restrict__ out, int n) {
    __shared__ int sm[1024];
    __shared__ int carry_s;
    const int t = threadIdx.x;
    if (t == 0) { carry_s = 0; out[0] = 0; }
    __syncthreads();
    for (int base = 0; base < n; base += 1024) {
        int v = (base + t < n) ? in[base + t] : 0;
        sm[t] = v;
        __syncthreads();
        for (int off = 1; off < 1024; off <<= 1) {
            int u = (t >= off) ? sm[t - off] : 0;
            __syncthreads();
            sm[t] += u;
            __syncthreads();
        }
        if (base + t < n) out[base + t + 1] = carry_s + sm[t];
        __syncthreads();
        if (t == 0) carry_s += sm[1023];
        __syncthreads();
    }
}

__global__ void scan_block_kernel(const int* __restrict__ deg, const int* __restrict__ blk_off,
                                  int* __restrict__ row_ptr, int n) {
    const int t = threadIdx.x;
    const int i = blockIdx.x * 256 + t;
    const int lane = t & 63, w = t >> 6;
    int x = (i < n) ? deg[i] : 0;
#pragma unroll
    for (int off = 1; off < 64; off <<= 1) {
        int u = __shfl_up(x, off, 64);
        if (lane >= off) x += u;
    }
    __shared__ int ws[4];
    if (lane == 63) ws[w] = x;
    __syncthreads();
    int add = blk_off[blockIdx.x];
#pragma unroll
    for (int j = 0; j < 4; ++j)
        if (j < w) add += ws[j];
    if (i < n) row_ptr[i + 1] = add + x;
    if (i == 0) row_ptr[0] = 0;
}

__global__ void scatter_kernel(const int* __restrict__ src, const int* __restrict__ dst,
                               const int* __restrict__ row_ptr, int* __restrict__ cursor,
                               int* __restrict__ csr_src, int E) {
    int i = blockIdx.x * 256 + threadIdx.x;
    if (i < E) {
        int d = dst[i];
        int pos = row_ptr[d] + atomicAdd(&cursor[d], 1);
        csr_src[pos] = src[i];
    }
}

// ======= all four weight transposes in ONE launch: WT[c][k] = bf16(W[k][c]) =======
__global__ void wt_all_kernel(const float* __restrict__ W1l, const float* __restrict__ W1r,
                              const float* __restrict__ W2l, const float* __restrict__ W2r,
                              ushort_t* __restrict__ T1l, ushort_t* __restrict__ T1r,
                              ushort_t* __restrict__ T2l, ushort_t* __restrict__ T2r) {
    const int b = blockIdx.x;
    const float* W;
    ushort_t* T;
    int K, idx;
    if (b < 64)       { W = W1l; T = T1l; K = 64;  idx = b * 256 + threadIdx.x; }
    else if (b < 128) { W = W1r; T = T1r; K = 64;  idx = (b - 64) * 256 + threadIdx.x; }
    else if (b < 384) { W = W2l; T = T2l; K = 256; idx = (b - 128) * 256 + threadIdx.x; }
    else              { W = W2r; T = T2r; K = 256; idx = (b - 384) * 256 + threadIdx.x; }
    const int k = idx >> 8, c = idx & 255;
    T[(size_t)c * K + k] = f2bf(W[idx]);
}

// ================= dual MFMA GEMM: outl = A@Wl+bl (fp16), outr = A@Wr+br (f32) ======
template <int K, bool A_FP32>
__global__ __launch_bounds__(256) void gemm_dual_kernel(const void* __restrict__ Av,
                                                        const ushort_t* __restrict__ BTl,
                                                        const ushort_t* __restrict__ BTr,
                                                        const float* __restrict__ bl,
                                                        const float* __restrict__ br,
                                                        _Float16* __restrict__ outl,
                                                        float* __restrict__ outr, int M) {
    __shared__ ushort_t As[64][40];       // [row][k], pad->80B stride
    __shared__ ushort_t Bs[2][128][40];   // [mat][col][k]
    const int t = threadIdx.x;
    const int row0 = blockIdx.x * 64, col0 = blockIdx.y * 128;
    const int wid = t >> 6, lane = t & 63;
    const int wr = wid >> 1, wc = wid & 1;
    const int frow = lane & 15, fk = (lane >> 4) * 8;
    const int arow = t >> 2, ak8 = (t & 3) * 8;
    const int srow = t >> 1, sks = (t & 1) * 16;

    float4v acc[2][2][4];
#pragma unroll
    for (int m = 0; m < 2; ++m)
#pragma unroll
        for (int i = 0; i < 2; ++i)
#pragma unroll
            for (int j = 0; j < 4; ++j) acc[m][i][j] = (float4v){0.f, 0.f, 0.f, 0.f};

    for (int k0 = 0; k0 < K; k0 += 32) {
        uint4 va = make_uint4(0, 0, 0, 0);
        if (row0 + arow < M) {
            if (A_FP32) {
                const float* Xf = (const float*)Av + (size_t)(row0 + arow) * K + k0 + ak8;
                float4 x0 = *(const float4*)(Xf + 0);
                float4 x1 = *(const float4*)(Xf + 4);
                va = make_uint4(pack2bf(x0.x, x0.y), pack2bf(x0.z, x0.w),
                                pack2bf(x1.x, x1.y), pack2bf(x1.z, x1.w));
            } else {
                va = *(const uint4*)((const ushort_t*)Av + (size_t)(row0 + arow) * K + k0 + ak8);
            }
        }
        *(uint4*)&As[arow][ak8] = va;
        {
            const ushort_t* Bp = BTl + (size_t)(col0 + srow) * K + k0 + sks;
            *(uint4*)&Bs[0][srow][sks + 0] = *(const uint4*)(Bp + 0);
            *(uint4*)&Bs[0][srow][sks + 8] = *(const uint4*)(Bp + 8);
            const ushort_t* Bq = BTr + (size_t)(col0 + srow) * K + k0 + sks;
            *(uint4*)&Bs[1][srow][sks + 0] = *(const uint4*)(Bq + 0);
            *(uint4*)&Bs[1][srow][sks + 8] = *(const uint4*)(Bq + 8);
        }
        __syncthreads();
        short8 af[2], bf[2][4];
#pragma unroll
        for (int mi = 0; mi < 2; ++mi)
            af[mi] = *(const short8*)&As[wr * 32 + mi * 16 + frow][fk];
#pragma unroll
        for (int m = 0; m < 2; ++m)
#pragma unroll
            for (int ni = 0; ni < 4; ++ni)
                bf[m][ni] = *(const short8*)&Bs[m][wc * 64 + ni * 16 + frow][fk];
#pragma unroll
        for (int m = 0; m < 2; ++m)
#pragma unroll
            for (int mi = 0; mi < 2; ++mi)
#pragma unroll
                for (int ni = 0; ni < 4; ++ni)
                    acc[m][mi][ni] = __builtin_amdgcn_mfma_f32_16x16x32_bf16(
                        af[mi], bf[m][ni], acc[m][mi][ni], 0, 0, 0);
        __syncthreads();
    }

    const int crow = (lane >> 4) * 4;
#pragma unroll
    for (int ni = 0; ni < 4; ++ni) {
        const int col = col0 + wc * 64 + ni * 16 + frow;
        const float bvl = bl[col], bvr = br[col];
#pragma unroll
        for (int mi = 0; mi < 2; ++mi) {
#pragma unroll
            for (int r = 0; r < 4; ++r) {
                const int row = row0 + wr * 32 + mi * 16 + crow + r;
                if (row < M) {
                    outl[(size_t)row * 256 + col] = (_Float16)(acc[0][mi][ni][r] + bvl);
                    outr[(size_t)row * 256 + col] = acc[1][mi][ni][r] + bvr;
                }
            }
        }
    }
}

// ============ fused GAT, lane = (edge_slot, channel_group), 2-deep prefetch ==========
__global__ __launch_bounds__(256) void gat_fused_kernel(const int* __restrict__ csr_src,
                                                        const int* __restrict__ row_ptr,
                                                        const _Float16* __restrict__ xl,
                                                        const float* __restrict__ xr,
                                                        const float* __restrict__ att,
                                                        const float* __restrict__ bias,
                                                        ushort_t* __restrict__ out_b,
                                                        float* __restrict__ out,
                                                        float* __restrict__ out_ls,
                                                        int n_nodes, int apply_elu) {
    __shared__ float red[8];
    const int d = blockIdx.x;
    const int t = threadIdx.x;
    const int w = t >> 6;            // head
    const int lane = t & 63;
    const int eg = lane >> 3;        // edge slot 0..7
    const int cg = lane & 7;         // channel group 0..7
    const int off = w * 64 + cg * 8;

    float xrf[8], avf[8];
    {
        const float* xrp = xr + (size_t)d * 256 + off;
        const float* ap  = att + off;
        *(float4*)&xrf[0] = *(const float4*)xrp;
        *(float4*)&xrf[4] = *(const float4*)(xrp + 4);
        *(float4*)&avf[0] = *(const float4*)ap;
        *(float4*)&avf[4] = *(const float4*)(ap + 4);
    }
#if HAS_FDOT2
    half2v xr2[4], a06[4], a04[4];   // lrelu(v)*a = (0.6a)*v + (0.4a)*|v|
#pragma unroll
    for (int i = 0; i < 4; ++i) {
        xr2[i] = (half2v){(_Float16)xrf[2 * i], (_Float16)xrf[2 * i + 1]};
        a06[i] = (half2v){(_Float16)(0.6f * avf[2 * i]), (_Float16)(0.6f * avf[2 * i + 1])};
        a04[i] = (half2v){(_Float16)(0.4f * avf[2 * i]), (_Float16)(0.4f * avf[2 * i + 1])};
    }
#endif
    const int e0 = row_ptr[d];
    const int deg = row_ptr[d + 1] - e0;
    const int cnt = deg + 1;             // + self loop at index deg
    const int nchunk = (cnt + 7) >> 3;
    float m = -INFINITY, s_loc = 0.f;
    float acc8[8] = {0.f, 0.f, 0.f, 0.f, 0.f, 0.f, 0.f, 0.f};

    // ---- pipeline prologue: gather chunk 0, index of chunk 1 ----
    union U8 { uint4 u; _Float16 h[8]; half2v h2[4]; };
    U8 gc;
    {
        const int j = eg;
        const int sn = (j < deg) ? csr_src[e0 + j] : d;
        gc.u = *(const uint4*)(xl + (size_t)sn * 256 + off);
    }
    int sn_nxt = d;
    if (nchunk > 1) {
        const int j = 8 + eg;
        sn_nxt = (j < deg) ? csr_src[e0 + j] : d;
    }

    for (int c = 0; c < nchunk; ++c) {
        const int base = c << 3;
        // prefetch: index for chunk c+2
        int sn_n2 = d;
        if (c + 2 < nchunk) {
            const int j = base + 16 + eg;
            sn_n2 = (j < deg) ? csr_src[e0 + j] : d;
        }
        // prefetch: gather for chunk c+1 (issued before compute on chunk c)
        U8 gn;
        gn.u = make_uint4(0, 0, 0, 0);
        if (c + 1 < nchunk) gn.u = *(const uint4*)(xl + (size_t)sn_nxt * 256 + off);

        // ---- compute on chunk c ----
        const int j = base + eg;
        float sc = 0.f;
#if HAS_FDOT2
#pragma unroll
        for (int i = 0; i < 4; ++i) {
            half2v v = gc.h2[i] + xr2[i];                      // v_pk_add_f16
            unsigned vb = __builtin_bit_cast(unsigned, v);
            half2v va = __builtin_bit_cast(half2v, vb & 0x7fff7fffu);  // packed |v|
            sc = __builtin_amdgcn_fdot2(v, a06[i], sc, false);
            sc = __builtin_amdgcn_fdot2(va, a04[i], sc, false);
        }
#else
#pragma unroll
        for (int i = 0; i < 8; ++i) {
            float v = (float)gc.h[i] + xrf[i];
            v = fmaxf(v, NEG_SLOPE * v);
            sc = fmaf(v, avf[i], sc);
        }
#endif
        sc += __shfl_xor(sc, 1, 64);
        sc += __shfl_xor(sc, 2, 64);
        sc += __shfl_xor(sc, 4, 64);         // lane holds full score of edge j
        sc = (j < cnt) ? sc : -INFINITY;     // mask pad edges
        float mx = fmaxf(sc, __shfl_xor(sc, 8, 64));
        mx = fmaxf(mx, __shfl_xor(mx, 16, 64));
        mx = fmaxf(mx, __shfl_xor(mx, 32, 64));
        if (mx > m + 8.f) {                  // defer-rescale: p bounded by e^8
            const float g2 = __expf(m - mx); // m==-inf -> 0
            s_loc *= g2;
#pragma unroll
            for (int i = 0; i < 8; ++i) acc8[i] *= g2;
            m = mx;
        }
        const float p = __expf(sc - m);      // pad -> exp(-inf)=0
        s_loc += p;
#pragma unroll
        for (int i = 0; i < 8; ++i)          // (float)h -> v_fma_mix_f32
            acc8[i] = fmaf(p, (float)gc.h[i], acc8[i]);

        gc = gn;
        sn_nxt = sn_n2;
    }

    float s_tot = s_loc;
    s_tot += __shfl_xor(s_tot, 8, 64);
    s_tot += __shfl_xor(s_tot, 16, 64);
    s_tot += __shfl_xor(s_tot, 32, 64);
#pragma unroll
    for (int i = 0; i < 8; ++i) {
        acc8[i] += __shfl_xor(acc8[i], 8, 64);
        acc8[i] += __shfl_xor(acc8[i], 16, 64);
        acc8[i] += __shfl_xor(acc8[i], 32, 64);
    }
    const float inv_s = 1.f / s_tot;
    float o8[8];
    const float* bp = bias + off;
#pragma unroll
    for (int i = 0; i < 8; ++i) o8[i] = acc8[i] * inv_s + bp[i];

    if (apply_elu) {
#pragma unroll
        for (int i = 0; i < 8; ++i) o8[i] = o8[i] > 0.f ? o8[i] : (__expf(o8[i]) - 1.f);
        if (eg == 0) {
            uint4 u;
            u.x = pack2bf(o8[0], o8[1]);
            u.y = pack2bf(o8[2], o8[3]);
            u.z = pack2bf(o8[4], o8[5]);
            u.w = pack2bf(o8[6], o8[7]);
            *(uint4*)(out_b + (size_t)d * 256 + off) = u;
        }
    } else {
        if (eg == 0) {
            float* op = out + (size_t)d * 256 + off;
            *(float4*)op       = make_float4(o8[0], o8[1], o8[2], o8[3]);
            *(float4*)(op + 4) = make_float4(o8[4], o8[5], o8[6], o8[7]);
        }
        // fused row log_softmax over 256 (values replicated across edge groups)
        float mx = o8[0];
#pragma unroll
        for (int i = 1; i < 8; ++i) mx = fmaxf(mx, o8[i]);
        mx = fmaxf(mx, __shfl_xor(mx, 1, 64));
        mx = fmaxf(mx, __shfl_xor(mx, 2, 64));
        mx = fmaxf(mx, __shfl_xor(mx, 4, 64));
        if (lane == 0) red[w] = mx;
        __syncthreads();
        const float m4 = fmaxf(fmaxf(red[0], red[1]), fmaxf(red[2], red[3]));
        float se = 0.f;
#pragma unroll
        for (int i = 0; i < 8; ++i) se += __expf(o8[i] - m4);
        se += __shfl_xor(se, 1, 64);
        se += __shfl_xor(se, 2, 64);
        se += __shfl_xor(se, 4, 64);
        if (lane == 0) red[4 + w] = se;
        __syncthreads();
        const float s4 = (red[4] + red[5]) + (red[6] + red[7]);
        const float lg = m4 + __logf(s4);
        if (eg == 0) {
            float* lp = out_ls + (size_t)d * 256 + off;
            *(float4*)lp       = make_float4(o8[0] - lg, o8[1] - lg, o8[2] - lg, o8[3] - lg);
            *(float4*)(lp + 4) = make_float4(o8[4] - lg, o8[5] - lg, o8[6] - lg, o8[7] - lg);
        }
    }
}

extern "C" void kernel_launch(void* const* d_in, const int* in_sizes, int n_in,
                              void* d_out, int out_size, void* d_ws, size_t ws_size,
                              hipStream_t stream) {
    const float* x     = (const float*)d_in[0];
    const int*   edge  = (const int*)d_in[1];
    const float* Wl1   = (const float*)d_in[2];
    const float* bl1   = (const float*)d_in[3];
    const float* Wr1   = (const float*)d_in[4];
    const float* br1   = (const float*)d_in[5];
    const float* att1  = (const float*)d_in[6];
    const float* bias1 = (const float*)d_in[7];
    const float* Wl2   = (const float*)d_in[8];
    const float* bl2   = (const float*)d_in[9];
    const float* Wr2   = (const float*)d_in[10];
    const float* br2   = (const float*)d_in[11];
    const float* att2  = (const float*)d_in[12];
    const float* bias2 = (const float*)d_in[13];

    const int N = in_sizes[0] / 64;  // 20000
    const int E = in_sizes[1] / 2;   // 500000
    const int* srcI = edge;
    const int* dstI = edge + E;

    const size_t NM = (size_t)N * 256;
    float*     XR   = (float*)d_ws;                // NM fp32 (xr)
    ushort_t*  XB   = (ushort_t*)(XR + NM);        // NM bf16 (layer-1 out = layer-2 A)
    _Float16*  XL   = (_Float16*)(XB + NM);        // NM fp16 (xl gather table)
    ushort_t*  WT1l = (ushort_t*)(XL + NM);        // 256*64
    ushort_t*  WT1r = WT1l + 256 * 64;             // 256*64
    ushort_t*  WT2l = WT1r + 256 * 64;             // 256*256
    ushort_t*  WT2r = WT2l + 256 * 256;            // 256*256
    int* deg     = (int*)(WT2r + 256 * 256);       // N
    int* row_ptr = deg + N;                        // N+1
    int* cursor  = row_ptr + N + 1;                // N
    int* partial = cursor + N;                     // nb
    int* blk_off = partial + ((N + 255) / 256);      // nb+1
    int* csr_src = blk_off + ((N + 255) / 256) + 1;  // E

    const int nb = (N + 255) / 256;
    const int e_grid = (E + 255) / 256;
    const dim3 gemm_grid((N + 63) / 64, 2);

    // ---- weight transposes to bf16 (one launch) ----
    wt_all_kernel<<<640, 256, 0, stream>>>(Wl1, Wr1, Wl2, Wr2, WT1l, WT1r, WT2l, WT2r);

    // ---- CSR by destination ----
    hipMemsetAsync(deg, 0, (size_t)N * sizeof(int), stream);
    hipMemsetAsync(cursor, 0, (size_t)N * sizeof(int), stream);
    hist_kernel<<<e_grid, 256, 0, stream>>>(dstI, deg, E);
    partial_kernel<<<nb, 256, 0, stream>>>(deg, partial, N);
    scan_kernel<<<1, 1024, 0, stream>>>(partial, blk_off, nb);
    scan_block_kernel<<<nb, 256, 0, stream>>>(deg, blk_off, row_ptr, N);
    scatter_kernel<<<e_grid, 256, 0, stream>>>(srcI, dstI, row_ptr, cursor, csr_src, E);

    // ---- layer 1 (A = x fp32, K=64): one dual GEMM -> XL (fp16) + XR (f32) ----
    gemm_dual_kernel<64, true><<<gemm_grid, 256, 0, stream>>>(x, WT1l, WT1r, bl1, br1,
                                                              XL, XR, N);
    gat_fused_kernel<<<N, 256, 0, stream>>>(csr_src, row_ptr, XL, XR, att1, bias1,
                                            XB, nullptr, nullptr, N, 1);

    // ---- layer 2 (A = XB bf16, K=256) ----
    gemm_dual_kernel<256, false><<<gemm_grid, 256, 0, stream>>>(XB, WT2l, WT2r, bl2, br2,
                                                                XL, XR, N);
    float* h2 = (float*)d_out;
    gat_fused_kernel<<<N, 256, 0, stream>>>(csr_src, row_ptr, XL, XR, att2, bias2,
                                            nullptr, h2, h2 + NM, N, 0);
}

// Round 9
// 208.805 us; speedup vs baseline: 10.4274x; 1.1265x over previous
//
#include <hip/hip_runtime.h>
#include <math.h>

#define NEG_SLOPE 0.2f

typedef unsigned short ushort_t;
typedef __attribute__((ext_vector_type(8))) short short8;
typedef __attribute__((ext_vector_type(4))) float float4v;
typedef _Float16 half2v __attribute__((ext_vector_type(2)));

#if defined(__has_builtin)
#if __has_builtin(__builtin_amdgcn_fdot2)
#define HAS_FDOT2 1
#endif
#endif

__device__ __forceinline__ ushort_t f2bf(float f) {           // RNE
    unsigned u = __float_as_uint(f);
    return (ushort_t)((u + 0x7fffu + ((u >> 16) & 1u)) >> 16);
}
__device__ __forceinline__ unsigned pack2bf(float lo, float hi) {
    return ((unsigned)f2bf(hi) << 16) | (unsigned)f2bf(lo);
}

// ================= CSR build =================
__global__ void hist_kernel(const int* __restrict__ dst, int* __restrict__ deg, int E) {
    int i = blockIdx.x * 256 + threadIdx.x;
    if (i < E) atomicAdd(&deg[dst[i]], 1);
}

__global__ void partial_kernel(const int* __restrict__ deg, int* __restrict__ partial, int n) {
    const int t = threadIdx.x;
    const int i = blockIdx.x * 256 + t;
    int v = (i < n) ? deg[i] : 0;
#pragma unroll
    for (int off = 32; off > 0; off >>= 1) v += __shfl_xor(v, off, 64);
    __shared__ int ws[4];
    if ((t & 63) == 0) ws[t >> 6] = v;
    __syncthreads();
    if (t == 0) partial[blockIdx.x] = ws[0] + ws[1] + ws[2] + ws[3];
}

__global__ void scan_kernel(const int* __restrict__ in, int* __restrict__ out, int n) {
    __shared__ int sm[1024];
    __shared__ int carry_s;
    const int t = threadIdx.x;
    if (t == 0) { carry_s = 0; out[0] = 0; }
    __syncthreads();
    for (int base = 0; base < n; base += 1024) {
        int v = (base + t < n) ? in[base + t] : 0;
        sm[t] = v;
        __syncthreads();
        for (int off = 1; off < 1024; off <<= 1) {
            int u = (t >= off) ? sm[t - off] : 0;
            __syncthreads();
            sm[t] += u;
            __syncthreads();
        }
        if (base + t < n) out[base + t + 1] = carry_s + sm[t];
        __syncthreads();
        if (t == 0) carry_s += sm[1023];
        __syncthreads();
    }
}

__global__ void scan_block_kernel(const int* __restrict__ deg, const int* __restrict__ blk_off,
                                  int* __restrict__ row_ptr, int n) {
    const int t = threadIdx.x;
    const int i = blockIdx.x * 256 + t;
    const int lane = t & 63, w = t >> 6;
    int x = (i < n) ? deg[i] : 0;
#pragma unroll
    for (int off = 1; off < 64; off <<= 1) {
        int u = __shfl_up(x, off, 64);
        if (lane >= off) x += u;
    }
    __shared__ int ws[4];
    if (lane == 63) ws[w] = x;
    __syncthreads();
    int add = blk_off[blockIdx.x];
#pragma unroll
    for (int j = 0; j < 4; ++j)
        if (j < w) add += ws[j];
    if (i < n) row_ptr[i + 1] = add + x;
    if (i == 0) row_ptr[0] = 0;
}

__global__ void scatter_kernel(const int* __restrict__ src, const int* __restrict__ dst,
                               const int* __restrict__ row_ptr, int* __restrict__ cursor,
                               int* __restrict__ csr_src, int E) {
    int i = blockIdx.x * 256 + threadIdx.x;
    if (i < E) {
        int d = dst[i];
        int pos = row_ptr[d] + atomicAdd(&cursor[d], 1);
        csr_src[pos] = src[i];
    }
}

// ======= all four weight transposes in ONE launch: WT[c][k] = bf16(W[k][c]) =======
__global__ void wt_all_kernel(const float* __restrict__ W1l, const float* __restrict__ W1r,
                              const float* __restrict__ W2l, const float* __restrict__ W2r,
                              ushort_t* __restrict__ T1l, ushort_t* __restrict__ T1r,
                              ushort_t* __restrict__ T2l, ushort_t* __restrict__ T2r) {
    const int b = blockIdx.x;
    const float* W;
    ushort_t* T;
    int K, idx;
    if (b < 64)       { W = W1l; T = T1l; K = 64;  idx = b * 256 + threadIdx.x; }
    else if (b < 128) { W = W1r; T = T1r; K = 64;  idx = (b - 64) * 256 + threadIdx.x; }
    else if (b < 384) { W = W2l; T = T2l; K = 256; idx = (b - 128) * 256 + threadIdx.x; }
    else              { W = W2r; T = T2r; K = 256; idx = (b - 384) * 256 + threadIdx.x; }
    const int k = idx >> 8, c = idx & 255;
    T[(size_t)c * K + k] = f2bf(W[idx]);
}

// ====== dual MFMA GEMM (double-buffered LDS): outl = A@Wl+bl (fp16), outr = A@Wr+br ==
template <int K, bool A_FP32>
__global__ __launch_bounds__(256) void gemm_dual_kernel(const void* __restrict__ Av,
                                                        const ushort_t* __restrict__ BTl,
                                                        const ushort_t* __restrict__ BTr,
                                                        const float* __restrict__ bl,
                                                        const float* __restrict__ br,
                                                        _Float16* __restrict__ outl,
                                                        float* __restrict__ outr, int M) {
    __shared__ ushort_t As[2][64][40];       // [buf][row][k]
    __shared__ ushort_t Bs[2][2][128][40];   // [buf][mat][col][k]
    const int t = threadIdx.x;
    const int row0 = blockIdx.x * 64, col0 = blockIdx.y * 128;
    const int wid = t >> 6, lane = t & 63;
    const int wr = wid >> 1, wc = wid & 1;
    const int frow = lane & 15, fk = (lane >> 4) * 8;
    const int arow = t >> 2, ak8 = (t & 3) * 8;
    const int srow = t >> 1, sks = (t & 1) * 16;

    float4v acc[2][2][4];
#pragma unroll
    for (int m = 0; m < 2; ++m)
#pragma unroll
        for (int i = 0; i < 2; ++i)
#pragma unroll
            for (int j = 0; j < 4; ++j) acc[m][i][j] = (float4v){0.f, 0.f, 0.f, 0.f};

    auto stage = [&](int buf, int k0) {
        uint4 va = make_uint4(0, 0, 0, 0);
        if (row0 + arow < M) {
            if (A_FP32) {
                const float* Xf = (const float*)Av + (size_t)(row0 + arow) * K + k0 + ak8;
                float4 x0 = *(const float4*)(Xf + 0);
                float4 x1 = *(const float4*)(Xf + 4);
                va = make_uint4(pack2bf(x0.x, x0.y), pack2bf(x0.z, x0.w),
                                pack2bf(x1.x, x1.y), pack2bf(x1.z, x1.w));
            } else {
                va = *(const uint4*)((const ushort_t*)Av + (size_t)(row0 + arow) * K + k0 + ak8);
            }
        }
        *(uint4*)&As[buf][arow][ak8] = va;
        const ushort_t* Bp = BTl + (size_t)(col0 + srow) * K + k0 + sks;
        *(uint4*)&Bs[buf][0][srow][sks + 0] = *(const uint4*)(Bp + 0);
        *(uint4*)&Bs[buf][0][srow][sks + 8] = *(const uint4*)(Bp + 8);
        const ushort_t* Bq = BTr + (size_t)(col0 + srow) * K + k0 + sks;
        *(uint4*)&Bs[buf][1][srow][sks + 0] = *(const uint4*)(Bq + 0);
        *(uint4*)&Bs[buf][1][srow][sks + 8] = *(const uint4*)(Bq + 8);
    };

    stage(0, 0);
    __syncthreads();
    int cur = 0;
    for (int k0 = 0; k0 < K; k0 += 32) {
        if (k0 + 32 < K) stage(cur ^ 1, k0 + 32);   // loads hide under MFMA below
        short8 af[2], bf[2][4];
#pragma unroll
        for (int mi = 0; mi < 2; ++mi)
            af[mi] = *(const short8*)&As[cur][wr * 32 + mi * 16 + frow][fk];
#pragma unroll
        for (int m = 0; m < 2; ++m)
#pragma unroll
            for (int ni = 0; ni < 4; ++ni)
                bf[m][ni] = *(const short8*)&Bs[cur][m][wc * 64 + ni * 16 + frow][fk];
#pragma unroll
        for (int m = 0; m < 2; ++m)
#pragma unroll
            for (int mi = 0; mi < 2; ++mi)
#pragma unroll
                for (int ni = 0; ni < 4; ++ni)
                    acc[m][mi][ni] = __builtin_amdgcn_mfma_f32_16x16x32_bf16(
                        af[mi], bf[m][ni], acc[m][mi][ni], 0, 0, 0);
        __syncthreads();
        cur ^= 1;
    }

    const int crow = (lane >> 4) * 4;
#pragma unroll
    for (int ni = 0; ni < 4; ++ni) {
        const int col = col0 + wc * 64 + ni * 16 + frow;
        const float bvl = bl[col], bvr = br[col];
#pragma unroll
        for (int mi = 0; mi < 2; ++mi) {
#pragma unroll
            for (int r = 0; r < 4; ++r) {
                const int row = row0 + wr * 32 + mi * 16 + crow + r;
                if (row < M) {
                    outl[(size_t)row * 256 + col] = (_Float16)(acc[0][mi][ni][r] + bvl);
                    outr[(size_t)row * 256 + col] = acc[1][mi][ni][r] + bvr;
                }
            }
        }
    }
}

// ============ fused GAT: ONE WAVE per node (all 4 heads), lane = (edge, ch_group) ====
// 4 independent waves per block (4 nodes). No LDS, no __syncthreads.
// lane = e*32 + g: e = edge slot 0..1, g = channel group 0..31 (head = g>>3).
__global__ __launch_bounds__(256) void gat_fused_kernel(const int* __restrict__ csr_src,
                                                        const int* __restrict__ row_ptr,
                                                        const _Float16* __restrict__ xl,
                                                        const float* __restrict__ xr,
                                                        const float* __restrict__ att,
                                                        const float* __restrict__ bias,
                                                        ushort_t* __restrict__ out_b,
                                                        float* __restrict__ out,
                                                        float* __restrict__ out_ls,
                                                        int n_nodes, int apply_elu) {
    const int wv = threadIdx.x >> 6;
    const int d = blockIdx.x * 4 + wv;
    if (d >= n_nodes) return;            // wave-uniform, no barriers anywhere
    const int lane = threadIdx.x & 63;
    const int e = lane >> 5;             // edge slot 0..1
    const int g = lane & 31;             // channel group (covers all 4 heads)
    const int off = g * 8;               // flat channel offset 0..255 step 8

    float xrf[8], avf[8];
    {
        const float* xrp = xr + (size_t)d * 256 + off;
        const float* ap  = att + off;
        *(float4*)&xrf[0] = *(const float4*)xrp;
        *(float4*)&xrf[4] = *(const float4*)(xrp + 4);
        *(float4*)&avf[0] = *(const float4*)ap;
        *(float4*)&avf[4] = *(const float4*)(ap + 4);
    }
#if HAS_FDOT2
    half2v xr2[4], a06[4], a04[4];       // lrelu(v)*a = (0.6a)*v + (0.4a)*|v|
#pragma unroll
    for (int i = 0; i < 4; ++i) {
        xr2[i] = (half2v){(_Float16)xrf[2 * i], (_Float16)xrf[2 * i + 1]};
        a06[i] = (half2v){(_Float16)(0.6f * avf[2 * i]), (_Float16)(0.6f * avf[2 * i + 1])};
        a04[i] = (half2v){(_Float16)(0.4f * avf[2 * i]), (_Float16)(0.4f * avf[2 * i + 1])};
    }
#endif
    const int e0 = row_ptr[d];
    const int deg = row_ptr[d + 1] - e0;
    const int cnt = deg + 1;             // + self loop at index deg
    const int nchunk = (cnt + 1) >> 1;   // 2 edges per chunk
    float m = -INFINITY, s_loc = 0.f;
    float acc8[8] = {0.f, 0.f, 0.f, 0.f, 0.f, 0.f, 0.f, 0.f};

    union U8 { uint4 u; _Float16 h[8]; half2v h2[4]; };
    // ---- pipeline prologue: gather chunk 0, index for chunk 1 ----
    U8 gc;
    {
        const int j = e;
        const int sn = (j < deg) ? csr_src[e0 + j] : d;
        gc.u = *(const uint4*)(xl + (size_t)sn * 256 + off);
    }
    int sn_nxt = d;
    if (nchunk > 1) {
        const int j = 2 + e;
        sn_nxt = (j < deg) ? csr_src[e0 + j] : d;
    }

    for (int c = 0; c < nchunk; ++c) {
        const int base = c << 1;
        // prefetch: index for chunk c+2
        int sn_n2 = d;
        if (c + 2 < nchunk) {
            const int j = base + 4 + e;
            sn_n2 = (j < deg) ? csr_src[e0 + j] : d;
        }
        // prefetch: gather for chunk c+1
        U8 gn;
        gn.u = make_uint4(0, 0, 0, 0);
        if (c + 1 < nchunk) gn.u = *(const uint4*)(xl + (size_t)sn_nxt * 256 + off);

        // ---- compute on chunk c ----
        const int j = base + e;
        float sc = 0.f;
#if HAS_FDOT2
#pragma unroll
        for (int i = 0; i < 4; ++i) {
            half2v v = gc.h2[i] + xr2[i];                      // v_pk_add_f16
            unsigned vb = __builtin_bit_cast(unsigned, v);
            half2v va = __builtin_bit_cast(half2v, vb & 0x7fff7fffu);  // packed |v|
            sc = __builtin_amdgcn_fdot2(v, a06[i], sc, false);
            sc = __builtin_amdgcn_fdot2(va, a04[i], sc, false);
        }
#else
#pragma unroll
        for (int i = 0; i < 8; ++i) {
            float v = (float)gc.h[i] + xrf[i];
            v = fmaxf(v, NEG_SLOPE * v);
            sc = fmaf(v, avf[i], sc);
        }
#endif
        // reduce over the 8 channel-groups of this head
        sc += __shfl_xor(sc, 1, 64);
        sc += __shfl_xor(sc, 2, 64);
        sc += __shfl_xor(sc, 4, 64);     // lane holds full score of (edge j, its head)
        sc = (j < cnt) ? sc : -INFINITY; // mask pad edge
        // per-head chunk max over the 2 edge slots
        float mx = fmaxf(sc, __shfl_xor(sc, 32, 64));
        if (mx > m + 8.f) {              // defer-rescale: p bounded by e^8
            const float g2 = __expf(m - mx);
            s_loc *= g2;
#pragma unroll
            for (int i = 0; i < 8; ++i) acc8[i] *= g2;
            m = mx;
        }
        const float p = __expf(sc - m);  // pad -> 0
        s_loc += p;
#pragma unroll
        for (int i = 0; i < 8; ++i)      // fp16 src -> v_fma_mix
            acc8[i] = fmaf(p, (float)gc.h[i], acc8[i]);

        gc = gn;
        sn_nxt = sn_n2;
    }

    // reduce across the 2 edge slots (once per node)
    float s_tot = s_loc + __shfl_xor(s_loc, 32, 64);
#pragma unroll
    for (int i = 0; i < 8; ++i) acc8[i] += __shfl_xor(acc8[i], 32, 64);
    const float inv_s = 1.f / s_tot;
    float o8[8];
    const float* bp = bias + off;
#pragma unroll
    for (int i = 0; i < 8; ++i) o8[i] = acc8[i] * inv_s + bp[i];

    if (apply_elu) {
#pragma unroll
        for (int i = 0; i < 8; ++i) o8[i] = o8[i] > 0.f ? o8[i] : (__expf(o8[i]) - 1.f);
        if (e == 0) {                    // 32 lanes x 16B = 512B contiguous
            uint4 u;
            u.x = pack2bf(o8[0], o8[1]);
            u.y = pack2bf(o8[2], o8[3]);
            u.z = pack2bf(o8[4], o8[5]);
            u.w = pack2bf(o8[6], o8[7]);
            *(uint4*)(out_b + (size_t)d * 256 + off) = u;
        }
    } else {
        if (e == 0) {
            float* op = out + (size_t)d * 256 + off;
            *(float4*)op       = make_float4(o8[0], o8[1], o8[2], o8[3]);
            *(float4*)(op + 4) = make_float4(o8[4], o8[5], o8[6], o8[7]);
        }
        // fused row log_softmax over all 256 channels — pure shfl, no LDS
        float mx = o8[0];
#pragma unroll
        for (int i = 1; i < 8; ++i) mx = fmaxf(mx, o8[i]);
        mx = fmaxf(mx, __shfl_xor(mx, 1, 64));
        mx = fmaxf(mx, __shfl_xor(mx, 2, 64));
        mx = fmaxf(mx, __shfl_xor(mx, 4, 64));
        mx = fmaxf(mx, __shfl_xor(mx, 8, 64));
        mx = fmaxf(mx, __shfl_xor(mx, 16, 64));   // row max (o8 replicated across e)
        float se = 0.f;
#pragma unroll
        for (int i = 0; i < 8; ++i) se += __expf(o8[i] - mx);
        se += __shfl_xor(se, 1, 64);
        se += __shfl_xor(se, 2, 64);
        se += __shfl_xor(se, 4, 64);
        se += __shfl_xor(se, 8, 64);
        se += __shfl_xor(se, 16, 64);
        const float lg = mx + __logf(se);
        if (e == 0) {
            float* lp = out_ls + (size_t)d * 256 + off;
            *(float4*)lp       = make_float4(o8[0] - lg, o8[1] - lg, o8[2] - lg, o8[3] - lg);
            *(float4*)(lp + 4) = make_float4(o8[4] - lg, o8[5] - lg, o8[6] - lg, o8[7] - lg);
        }
    }
}

extern "C" void kernel_launch(void* const* d_in, const int* in_sizes, int n_in,
                              void* d_out, int out_size, void* d_ws, size_t ws_size,
                              hipStream_t stream) {
    const float* x     = (const float*)d_in[0];
    const int*   edge  = (const int*)d_in[1];
    const float* Wl1   = (const float*)d_in[2];
    const float* bl1   = (const float*)d_in[3];
    const float* Wr1   = (const float*)d_in[4];
    const float* br1   = (const float*)d_in[5];
    const float* att1  = (const float*)d_in[6];
    const float* bias1 = (const float*)d_in[7];
    const float* Wl2   = (const float*)d_in[8];
    const float* bl2   = (const float*)d_in[9];
    const float* Wr2   = (const float*)d_in[10];
    const float* br2   = (const float*)d_in[11];
    const float* att2  = (const float*)d_in[12];
    const float* bias2 = (const float*)d_in[13];

    const int N = in_sizes[0] / 64;  // 20000
    const int E = in_sizes[1] / 2;   // 500000
    const int* srcI = edge;
    const int* dstI = edge + E;

    const size_t NM = (size_t)N * 256;
    float*     XR   = (float*)d_ws;                // NM fp32 (xr)
    ushort_t*  XB   = (ushort_t*)(XR + NM);        // NM bf16 (layer-1 out = layer-2 A)
    _Float16*  XL   = (_Float16*)(XB + NM);        // NM fp16 (xl gather table)
    ushort_t*  WT1l = (ushort_t*)(XL + NM);        // 256*64
    ushort_t*  WT1r = WT1l + 256 * 64;             // 256*64
    ushort_t*  WT2l = WT1r + 256 * 64;             // 256*256
    ushort_t*  WT2r = WT2l + 256 * 256;            // 256*256
    int* deg     = (int*)(WT2r + 256 * 256);       // N
    int* row_ptr = deg + N;                        // N+1
    int* cursor  = row_ptr + N + 1;                // N
    int* partial = cursor + N;                     // nb
    int* blk_off = partial + ((N + 255) / 256);      // nb+1
    int* csr_src = blk_off + ((N + 255) / 256) + 1;  // E

    const int nb = (N + 255) / 256;
    const int e_grid = (E + 255) / 256;
    const dim3 gemm_grid((N + 63) / 64, 2);
    const int gat_grid = (N + 3) / 4;

    // ---- weight transposes to bf16 (one launch) ----
    wt_all_kernel<<<640, 256, 0, stream>>>(Wl1, Wr1, Wl2, Wr2, WT1l, WT1r, WT2l, WT2r);

    // ---- CSR by destination ----
    hipMemsetAsync(deg, 0, (size_t)N * sizeof(int), stream);
    hipMemsetAsync(cursor, 0, (size_t)N * sizeof(int), stream);
    hist_kernel<<<e_grid, 256, 0, stream>>>(dstI, deg, E);
    partial_kernel<<<nb, 256, 0, stream>>>(deg, partial, N);
    scan_kernel<<<1, 1024, 0, stream>>>(partial, blk_off, nb);
    scan_block_kernel<<<nb, 256, 0, stream>>>(deg, blk_off, row_ptr, N);
    scatter_kernel<<<e_grid, 256, 0, stream>>>(srcI, dstI, row_ptr, cursor, csr_src, E);

    // ---- layer 1 (A = x fp32, K=64): one dual GEMM -> XL (fp16) + XR (f32) ----
    gemm_dual_kernel<64, true><<<gemm_grid, 256, 0, stream>>>(x, WT1l, WT1r, bl1, br1,
                                                              XL, XR, N);
    gat_fused_kernel<<<gat_grid, 256, 0, stream>>>(csr_src, row_ptr, XL, XR, att1, bias1,
                                                   XB, nullptr, nullptr, N, 1);

    // ---- layer 2 (A = XB bf16, K=256) ----
    gemm_dual_kernel<256, false><<<gemm_grid, 256, 0, stream>>>(XB, WT2l, WT2r, bl2, br2,
                                                                XL, XR, N);
    float* h2 = (float*)d_out;
    gat_fused_kernel<<<gat_grid, 256, 0, stream>>>(csr_src, row_ptr, XL, XR, att2, bias2,
                                                   nullptr, h2, h2 + NM, N, 0);
}